// Round 1
// baseline (1185.719 us; speedup 1.0000x reference)
//
#include <hip/hip_runtime.h>
#include <hip/hip_bf16.h>

typedef unsigned short u16;

static __device__ __forceinline__ float bf2f(u16 x) {
    unsigned int u = ((unsigned int)x) << 16;
    return __uint_as_float(u);
}
static __device__ __forceinline__ u16 f2bf(float f) {
    unsigned int u = __float_as_uint(f);
    unsigned int r = (u + 0x7fffu + ((u >> 16) & 1u)) >> 16;
    return (u16)r;
}
static __device__ __forceinline__ float sigmoidf(float x) {
    return 1.0f / (1.0f + expf(-x));
}

// ---------------- K0: zero text_seg_probs + loss slot ----------------
__global__ void k_zero(float* __restrict__ out) {
    int t = blockIdx.x * 256 + threadIdx.x;
    if (t < 2048) out[t] = 0.0f;
    if (t == 0) out[536576] = 0.0f;
}

// ---------------- K1: xg = gather(emb)[65536,128] @ Wi^T[128,384] + bi -> bf16 ----------------
// grid (1024, 6), block 256. Tile 64 tokens x 64 gates, K=128 fully staged.
__global__ void k_xg(const int* __restrict__ ids, const float* __restrict__ emb,
                     const float* __restrict__ Wi, const float* __restrict__ bi,
                     u16* __restrict__ xg) {
    __shared__ float As[128][68];  // transposed A tile [k][m]
    __shared__ float Bs[128][68];  // transposed B tile [k][n]
    const int m0 = blockIdx.x * 64;
    const int n0 = blockIdx.y * 64;
    const int t = threadIdx.x;
    {
        const int r = t & 63, kb = (t >> 6) * 32;
        const int id = ids[m0 + r];
        const float* srcA = emb + (long)id * 128 + kb;
        const float* srcB = Wi + (long)(n0 + r) * 128 + kb;
#pragma unroll
        for (int kk = 0; kk < 32; kk += 4) {
            float4 a = *(const float4*)(srcA + kk);
            As[kb + kk + 0][r] = a.x; As[kb + kk + 1][r] = a.y;
            As[kb + kk + 2][r] = a.z; As[kb + kk + 3][r] = a.w;
            float4 b = *(const float4*)(srcB + kk);
            Bs[kb + kk + 0][r] = b.x; Bs[kb + kk + 1][r] = b.y;
            Bs[kb + kk + 2][r] = b.z; Bs[kb + kk + 3][r] = b.w;
        }
    }
    __syncthreads();
    const int tx = t & 15, ty = t >> 4;
    float acc[4][4] = {};
#pragma unroll 4
    for (int k = 0; k < 128; k++) {
        float4 a4 = *(const float4*)&As[k][ty * 4];
        float4 b4 = *(const float4*)&Bs[k][tx * 4];
        acc[0][0] += a4.x * b4.x; acc[0][1] += a4.x * b4.y; acc[0][2] += a4.x * b4.z; acc[0][3] += a4.x * b4.w;
        acc[1][0] += a4.y * b4.x; acc[1][1] += a4.y * b4.y; acc[1][2] += a4.y * b4.z; acc[1][3] += a4.y * b4.w;
        acc[2][0] += a4.z * b4.x; acc[2][1] += a4.z * b4.y; acc[2][2] += a4.z * b4.z; acc[2][3] += a4.z * b4.w;
        acc[3][0] += a4.w * b4.x; acc[3][1] += a4.w * b4.y; acc[3][2] += a4.w * b4.z; acc[3][3] += a4.w * b4.w;
    }
    float bb[4];
#pragma unroll
    for (int j = 0; j < 4; j++) bb[j] = bi[n0 + tx * 4 + j];
#pragma unroll
    for (int i = 0; i < 4; i++) {
        const int m = m0 + ty * 4 + i;
        ushort4 o;
        o.x = f2bf(acc[i][0] + bb[0]);
        o.y = f2bf(acc[i][1] + bb[1]);
        o.z = f2bf(acc[i][2] + bb[2]);
        o.w = f2bf(acc[i][3] + bb[3]);
        *(ushort4*)(xg + (long)m * 384 + n0 + tx * 4) = o;
    }
}

// ---------------- K2: GRU scan over 32 steps ----------------
// grid 256 (8 seqs/block), block 256: thread = (j = hidden idx 0..127, sp = seq-quad 0/1)
__global__ void k_scan(const u16* __restrict__ xg, const float* __restrict__ Wh,
                       const float* __restrict__ bh, float* __restrict__ tf_out, int dir) {
    __shared__ u16 whl[3][128][128];   // [gate][i][j] = Wh[gate*128+j][i], bf16
    __shared__ float h_lds[128][8];    // [hidden i][seq]
    const int t = threadIdx.x;
    const int j = t & 127, sp = t >> 7;

    if (sp == 0) {
        for (int c = 0; c < 3; c++) {
            const float* src = Wh + (long)(c * 128 + j) * 128;
            for (int i = 0; i < 128; i++) whl[c][i][j] = f2bf(src[i]);
        }
    }
    *(float4*)&((float*)h_lds)[t * 4] = make_float4(0.f, 0.f, 0.f, 0.f);

    const float bh_r = bh[j], bh_z = bh[128 + j], bh_n = bh[256 + j];
    float hreg[4] = {0.f, 0.f, 0.f, 0.f};
    float macc[4] = {0.f, 0.f, 0.f, 0.f};
    const int seq0 = blockIdx.x * 8 + sp * 4;
    __syncthreads();

    for (int tt = 0; tt < 32; tt++) {
        const int tp = dir ? (31 - tt) : tt;
        float xr[4], xz[4], xn[4];
#pragma unroll
        for (int s = 0; s < 4; s++) {
            const u16* p = xg + ((long)(seq0 + s) * 32 + tp) * 384 + j;
            xr[s] = bf2f(p[0]); xz[s] = bf2f(p[128]); xn[s] = bf2f(p[256]);
        }
        float aR[4] = {bh_r, bh_r, bh_r, bh_r};
        float aZ[4] = {bh_z, bh_z, bh_z, bh_z};
        float aN[4] = {bh_n, bh_n, bh_n, bh_n};
#pragma unroll 4
        for (int i = 0; i < 128; i++) {
            float4 hv = *(const float4*)&h_lds[i][sp * 4];
            float wr = bf2f(whl[0][i][j]);
            float wz = bf2f(whl[1][i][j]);
            float wn = bf2f(whl[2][i][j]);
            aR[0] += wr * hv.x; aR[1] += wr * hv.y; aR[2] += wr * hv.z; aR[3] += wr * hv.w;
            aZ[0] += wz * hv.x; aZ[1] += wz * hv.y; aZ[2] += wz * hv.z; aZ[3] += wz * hv.w;
            aN[0] += wn * hv.x; aN[1] += wn * hv.y; aN[2] += wn * hv.z; aN[3] += wn * hv.w;
        }
        __syncthreads();
#pragma unroll
        for (int s = 0; s < 4; s++) {
            float r = sigmoidf(xr[s] + aR[s]);
            float z = sigmoidf(xz[s] + aZ[s]);
            float n = tanhf(xn[s] + r * aN[s]);
            float h = (1.0f - z) * n + z * hreg[s];
            hreg[s] = h;
            macc[s] += h;
        }
        *(float4*)&h_lds[j][sp * 4] = make_float4(hreg[0], hreg[1], hreg[2], hreg[3]);
        __syncthreads();
    }
#pragma unroll
    for (int s = 0; s < 4; s++)
        tf_out[(long)(seq0 + s) * 256 + dir * 128 + j] = macc[s] * (1.0f / 32.0f);
}

// ---------------- K3: text summary scorer (tanh MLP + sigmoid) ----------------
// grid 2048 (one row), block 128
__global__ void k_tsum(const float* __restrict__ tf, const float* __restrict__ W1,
                       const float* __restrict__ b1, const float* __restrict__ w2,
                       const float* __restrict__ b2, float* __restrict__ out) {
    __shared__ float x[256];
    __shared__ float wsum[2];
    const int row = blockIdx.x, t = threadIdx.x;
    x[t] = tf[(long)row * 256 + t];
    x[t + 128] = tf[(long)row * 256 + 128 + t];
    __syncthreads();
    float acc = 0.f;
    const float* w = W1 + (long)t * 256;
#pragma unroll 8
    for (int i = 0; i < 256; i += 4) {
        float4 w4 = *(const float4*)(w + i);
        acc += w4.x * x[i] + w4.y * x[i + 1] + w4.z * x[i + 2] + w4.w * x[i + 3];
    }
    float h = tanhf(acc + b1[t]) * w2[t];
    for (int o = 32; o > 0; o >>= 1) h += __shfl_xor(h, o);
    if ((t & 63) == 0) wsum[t >> 6] = h;
    __syncthreads();
    if (t == 0) out[row] = sigmoidf(wsum[0] + wsum[1] + b2[0]);
}

// ---------------- K4: fused video scorers (vsum tanh + vts relu) ----------------
// grid 512 (8 rows/block), block 256
__global__ void k_video(const float* __restrict__ vf,
                        const float* __restrict__ Wv, const float* __restrict__ bv,
                        const float* __restrict__ w2v, const float* __restrict__ b2v,
                        const float* __restrict__ Wt, const float* __restrict__ bt,
                        const float* __restrict__ w2t, const float* __restrict__ b2t,
                        float* __restrict__ out_vsum, float* __restrict__ out_vseg) {
    __shared__ float x[8][1024];
    __shared__ float red[8][2][4];
    const int r0 = blockIdx.x * 8, t = threadIdx.x;
    const float4* src = (const float4*)(vf + (long)r0 * 1024);
    for (int i = t; i < 2048; i += 256) ((float4*)&x[0][0])[i] = src[i];
    __syncthreads();
    float av[8] = {}, at8[8] = {};
    const float* wv = Wv + (long)t * 1024;
    const float* wt = Wt + (long)t * 1024;
    for (int i = 0; i < 1024; i += 4) {
        float4 w4v = *(const float4*)(wv + i);
        float4 w4t = *(const float4*)(wt + i);
#pragma unroll
        for (int r = 0; r < 8; r++) {
            float4 x4 = *(const float4*)&x[r][i];
            av[r]  += w4v.x * x4.x + w4v.y * x4.y + w4v.z * x4.z + w4v.w * x4.w;
            at8[r] += w4t.x * x4.x + w4t.y * x4.y + w4t.z * x4.z + w4t.w * x4.w;
        }
    }
    const float bv1 = bv[t], bt1 = bt[t], w2vv = w2v[t], w2tt = w2t[t];
    const int lane = t & 63, wv_id = t >> 6;
#pragma unroll
    for (int r = 0; r < 8; r++) {
        float hv = tanhf(av[r] + bv1) * w2vv;
        float ht = fmaxf(at8[r] + bt1, 0.0f) * w2tt;
        for (int o = 32; o > 0; o >>= 1) { hv += __shfl_xor(hv, o); ht += __shfl_xor(ht, o); }
        if (lane == 0) { red[r][0][wv_id] = hv; red[r][1][wv_id] = ht; }
    }
    __syncthreads();
    if (t < 8) {
        float sv = red[t][0][0] + red[t][0][1] + red[t][0][2] + red[t][0][3] + b2v[0];
        out_vsum[r0 + t] = sigmoidf(sv);
    } else if (t < 16) {
        int r = t - 8;
        float st = red[r][1][0] + red[r][1][1] + red[r][1][2] + red[r][1][3] + b2t[0];
        out_vseg[r0 + r] = sigmoidf(st);
    }
}

// ---------------- K5a: E_proj = (tf * tsp) @ tproj_W^T + b ----------------
// grid 256 (8 rows/block), block 256 (thread = out col)
__global__ void k_eproj(const float* __restrict__ tf, const float* __restrict__ tsp,
                        const float* __restrict__ W, const float* __restrict__ b,
                        float* __restrict__ E) {
    __shared__ float x[8][256];
    __shared__ float p[8];
    const int r0 = blockIdx.x * 8, t = threadIdx.x;
    const float4* src = (const float4*)(tf + (long)r0 * 256);
    for (int i = t; i < 512; i += 256) ((float4*)&x[0][0])[i] = src[i];
    if (t < 8) p[t] = tsp[r0 + t];
    __syncthreads();
    float acc[8] = {};
    const float* w = W + (long)t * 256;
    for (int i = 0; i < 256; i += 4) {
        float4 w4 = *(const float4*)(w + i);
#pragma unroll
        for (int r = 0; r < 8; r++) {
            float4 x4 = *(const float4*)&x[r][i];
            acc[r] += w4.x * x4.x + w4.y * x4.y + w4.z * x4.z + w4.w * x4.w;
        }
    }
    const float bb = b[t];
#pragma unroll
    for (int r = 0; r < 8; r++) E[(long)(r0 + r) * 256 + t] = bb + p[r] * acc[r];
}

// ---------------- K5b: V_proj = (vf * vsp) @ vproj_W^T + b ----------------
// grid 512 (8 rows/block), block 256
__global__ void k_vproj(const float* __restrict__ vf, const float* __restrict__ vsp,
                        const float* __restrict__ W, const float* __restrict__ b,
                        float* __restrict__ V) {
    __shared__ float x[8][1024];
    __shared__ float p[8];
    const int r0 = blockIdx.x * 8, t = threadIdx.x;
    const float4* src = (const float4*)(vf + (long)r0 * 1024);
    for (int i = t; i < 2048; i += 256) ((float4*)&x[0][0])[i] = src[i];
    if (t < 8) p[t] = vsp[r0 + t];
    __syncthreads();
    float acc[8] = {};
    const float* w = W + (long)t * 1024;
    for (int i = 0; i < 1024; i += 4) {
        float4 w4 = *(const float4*)(w + i);
#pragma unroll
        for (int r = 0; r < 8; r++) {
            float4 x4 = *(const float4*)&x[r][i];
            acc[r] += w4.x * x4.x + w4.y * x4.y + w4.z * x4.z + w4.w * x4.w;
        }
    }
    const float bb = b[t];
#pragma unroll
    for (int r = 0; r < 8; r++) V[(long)(r0 + r) * 256 + t] = bb + p[r] * acc[r];
}

// ---------------- K6: row L2-normalize E (2048 rows) and V (4096 rows) in place ----------------
// grid 1536, block 256 (wave per row)
__global__ void k_norm(float* __restrict__ E, float* __restrict__ V) {
    const int w = threadIdx.x >> 6, lane = threadIdx.x & 63;
    const int row = blockIdx.x * 4 + w;
    float* ptr = (row < 2048) ? (E + (long)row * 256) : (V + (long)(row - 2048) * 256);
    float4 v = ((float4*)ptr)[lane];
    float s = v.x * v.x + v.y * v.y + v.z * v.z + v.w * v.w;
    for (int o = 32; o > 0; o >>= 1) s += __shfl_xor(s, o);
    float sc = 1.0f / (sqrtf(s) + 1e-12f);
    v.x *= sc; v.y *= sc; v.z *= sc; v.w *= sc;
    ((float4*)ptr)[lane] = v;
}

// ---------------- K7: C = 1 - En . Vn^T  and Km = exp(-C/reg) ----------------
// grid (16, 8), block 256 (thread = m)
__global__ void k_cost(const float* __restrict__ E, const float* __restrict__ V,
                       float* __restrict__ C, float* __restrict__ Km) {
    __shared__ float en[16][256];
    const int b = blockIdx.x, k0 = blockIdx.y * 16, t = threadIdx.x;
    const float4* esrc = (const float4*)(E + ((long)b * 128 + k0) * 256);
    for (int i = t; i < 1024; i += 256) ((float4*)&en[0][0])[i] = esrc[i];
    __syncthreads();
    float acc[16] = {};
    const float* vrow = V + ((long)b * 256 + t) * 256;
    for (int i = 0; i < 256; i += 4) {
        float4 v4 = *(const float4*)(vrow + i);
#pragma unroll
        for (int k = 0; k < 16; k++) {
            float4 e4 = *(const float4*)&en[k][i];
            acc[k] += e4.x * v4.x + e4.y * v4.y + e4.z * v4.z + e4.w * v4.w;
        }
    }
#pragma unroll
    for (int k = 0; k < 16; k++) {
        float c = 1.0f - acc[k];
        long idx = (long)b * 32768 + (long)(k0 + k) * 256 + t;
        C[idx] = c;
        Km[idx] = expf(-20.0f * c);
    }
}

// ---------------- K8: Sinkhorn iterations + T + loss ----------------
// grid 16 (one per batch), block 512
__global__ void k_sink(const float* __restrict__ C, const float* __restrict__ Km,
                       float* __restrict__ T, float* __restrict__ loss) {
    __shared__ float u[128];
    __shared__ float v[256];
    __shared__ float red[8];
    const int b = blockIdx.x, t = threadIdx.x;
    const float* Kb = Km + (long)b * 32768;
    const float* Cb = C + (long)b * 32768;
    if (t < 128) u[t] = 1.0f / 128.0f;
    if (t < 256) v[t] = 1.0f / 256.0f;
    __syncthreads();
    for (int it = 0; it < 10; it++) {
        {   // u = mu / (Km @ v + 1e-8);  t = k*4 + q, q covers 64 m's
            const int k = t >> 2, q = t & 3;
            const float* kr = Kb + (long)k * 256 + q * 64;
            float s = 0.f;
#pragma unroll 4
            for (int m = 0; m < 64; m += 4) {
                float4 k4 = *(const float4*)(kr + m);
                float4 vv = *(const float4*)&v[q * 64 + m];
                s += k4.x * vv.x + k4.y * vv.y + k4.z * vv.z + k4.w * vv.w;
            }
            s += __shfl_xor(s, 1);
            s += __shfl_xor(s, 2);
            float un = (1.0f / 128.0f) / (s + 1e-8f);
            u[k] = un;   // 4 lanes write identical value
            __syncthreads();
        }
        {   // v = nu / (Km^T @ u + 1e-8);  t = m*2 + q, q covers 64 k's
            const int m = t >> 1, q = t & 1;
            float s = 0.f;
            for (int k = 0; k < 64; k += 4) {
                float4 u4 = *(const float4*)&u[q * 64 + k];
                s += Kb[(long)(q * 64 + k + 0) * 256 + m] * u4.x;
                s += Kb[(long)(q * 64 + k + 1) * 256 + m] * u4.y;
                s += Kb[(long)(q * 64 + k + 2) * 256 + m] * u4.z;
                s += Kb[(long)(q * 64 + k + 3) * 256 + m] * u4.w;
            }
            s += __shfl_xor(s, 1);
            float vn = (1.0f / 256.0f) / (s + 1e-8f);
            v[m] = vn;   // 2 lanes write identical value
            __syncthreads();
        }
    }
    float part = 0.f;
    for (int i = 0; i < 64; i++) {
        int idx = i * 512 + t;
        int k = idx >> 8, m = idx & 255;
        float tv = u[k] * Kb[idx] * v[m];
        T[(long)b * 32768 + idx] = tv;
        part += tv * Cb[idx];
    }
    for (int o = 32; o > 0; o >>= 1) part += __shfl_xor(part, o);
    if ((t & 63) == 0) red[t >> 6] = part;
    __syncthreads();
    if (t == 0) {
        float s = red[0] + red[1] + red[2] + red[3] + red[4] + red[5] + red[6] + red[7];
        atomicAdd(loss, s * (1.0f / 16.0f));
    }
}

extern "C" void kernel_launch(void* const* d_in, const int* in_sizes, int n_in,
                              void* d_out, int out_size, void* d_ws, size_t ws_size,
                              hipStream_t stream) {
    const int*   ids  = (const int*)d_in[0];
    // d_in[1] = attention_mask (all ones, unused by the reference math)
    const float* vf   = (const float*)d_in[2];
    const float* emb  = (const float*)d_in[3];
    const float* WiF  = (const float*)d_in[4];
    const float* WhF  = (const float*)d_in[5];
    const float* biF  = (const float*)d_in[6];
    const float* bhF  = (const float*)d_in[7];
    const float* WiB  = (const float*)d_in[8];
    const float* WhB  = (const float*)d_in[9];
    const float* biB  = (const float*)d_in[10];
    const float* bhB  = (const float*)d_in[11];
    const float* tpW  = (const float*)d_in[12];
    const float* tpb  = (const float*)d_in[13];
    const float* vpW  = (const float*)d_in[14];
    const float* vpb  = (const float*)d_in[15];
    const float* tsW1 = (const float*)d_in[16];
    const float* tsb1 = (const float*)d_in[17];
    const float* tsw2 = (const float*)d_in[18];
    const float* tsb2 = (const float*)d_in[19];
    const float* vsW1 = (const float*)d_in[20];
    const float* vsb1 = (const float*)d_in[21];
    const float* vsw2 = (const float*)d_in[22];
    const float* vsb2 = (const float*)d_in[23];
    const float* vtW1 = (const float*)d_in[24];
    const float* vtb1 = (const float*)d_in[25];
    const float* vtw2 = (const float*)d_in[26];
    const float* vtb2 = (const float*)d_in[27];
    float* out = (float*)d_out;

    // workspace layout (bytes):
    //   XG  bf16 [2048][32][384] : 0            .. 50,331,648
    //   E   f32  [2048][256]     : 50,331,648   ..  +2,097,152
    //   V   f32  [4096][256]     : 52,428,800   ..  +4,194,304
    //   C   f32  [16][128][256]  : 56,623,104   ..  +2,097,152
    //   Km  f32  [16][128][256]  : 58,720,256   ..  +2,097,152   (total 60,817,408)
    char* ws = (char*)d_ws;
    u16*   XG = (u16*)ws;
    float* E  = (float*)(ws + 50331648);
    float* V  = (float*)(ws + 52428800);
    float* C  = (float*)(ws + 56623104);
    float* Km = (float*)(ws + 58720256);

    float* tf   = out + 2048;      // text_features (16,128,256)
    float* vseg = out + 526336;    // video_seg_probs (16,256)
    float* tsp  = out + 530432;    // text_summ_probs (16,128)
    float* vsp  = out + 532480;    // video_summ_probs (16,256)
    float* loss = out + 536576;    // ot_loss scalar
    float* T    = out + 536577;    // T (16,128,256)

    k_zero<<<8, 256, 0, stream>>>(out);

    // forward direction (XG buffer reused for both dirs; stream order serializes)
    k_xg<<<dim3(1024, 6), 256, 0, stream>>>(ids, emb, WiF, biF, XG);
    k_scan<<<256, 256, 0, stream>>>(XG, WhF, bhF, tf, 0);
    // backward direction
    k_xg<<<dim3(1024, 6), 256, 0, stream>>>(ids, emb, WiB, biB, XG);
    k_scan<<<256, 256, 0, stream>>>(XG, WhB, bhB, tf, 1);

    k_tsum<<<2048, 128, 0, stream>>>(tf, tsW1, tsb1, tsw2, tsb2, tsp);
    k_video<<<512, 256, 0, stream>>>(vf, vsW1, vsb1, vsw2, vsb2,
                                     vtW1, vtb1, vtw2, vtb2, vsp, vseg);

    k_eproj<<<256, 256, 0, stream>>>(tf, tsp, tpW, tpb, E);
    k_vproj<<<512, 256, 0, stream>>>(vf, vsp, vpW, vpb, V);
    k_norm<<<1536, 256, 0, stream>>>(E, V);
    k_cost<<<dim3(16, 8), 256, 0, stream>>>(E, V, C, Km);
    k_sink<<<16, 512, 0, stream>>>(C, Km, T, loss);
}

// Round 4
// 931.612 us; speedup vs baseline: 1.2728x; 1.2728x over previous
//
#include <hip/hip_runtime.h>
#include <hip/hip_bf16.h>

typedef unsigned short u16;
typedef __attribute__((ext_vector_type(8))) short short8;
typedef __attribute__((ext_vector_type(4))) float f32x4;

static __device__ __forceinline__ float bf2f(u16 x) {
    unsigned int u = ((unsigned int)x) << 16;
    return __uint_as_float(u);
}
static __device__ __forceinline__ u16 f2bf(float f) {
    unsigned int u = __float_as_uint(f);
    unsigned int r = (u + 0x7fffu + ((u >> 16) & 1u)) >> 16;
    return (u16)r;
}
static __device__ __forceinline__ float sigmoidf(float x) {
    return 1.0f / (1.0f + expf(-x));
}

// ---------------- K0: zero text_seg_probs + loss slot ----------------
__global__ void k_zero(float* __restrict__ out) {
    int t = blockIdx.x * 256 + threadIdx.x;
    if (t < 2048) out[t] = 0.0f;
    if (t == 0) out[536576] = 0.0f;
}

// ---------------- K1: xg = gather(emb)[65536,128] @ Wi^T[128,384] + bi -> bf16 ----------------
// grid (1024, 6), block 256. Tile 64 tokens x 64 gates, K=128 fully staged.
__global__ void k_xg(const int* __restrict__ ids, const float* __restrict__ emb,
                     const float* __restrict__ Wi, const float* __restrict__ bi,
                     u16* __restrict__ xg) {
    __shared__ float As[128][68];  // transposed A tile [k][m]
    __shared__ float Bs[128][68];  // transposed B tile [k][n]
    const int m0 = blockIdx.x * 64;
    const int n0 = blockIdx.y * 64;
    const int t = threadIdx.x;
    {
        const int r = t & 63, kb = (t >> 6) * 32;
        const int id = ids[m0 + r];
        const float* srcA = emb + (long)id * 128 + kb;
        const float* srcB = Wi + (long)(n0 + r) * 128 + kb;
#pragma unroll
        for (int kk = 0; kk < 32; kk += 4) {
            float4 a = *(const float4*)(srcA + kk);
            As[kb + kk + 0][r] = a.x; As[kb + kk + 1][r] = a.y;
            As[kb + kk + 2][r] = a.z; As[kb + kk + 3][r] = a.w;
            float4 b = *(const float4*)(srcB + kk);
            Bs[kb + kk + 0][r] = b.x; Bs[kb + kk + 1][r] = b.y;
            Bs[kb + kk + 2][r] = b.z; Bs[kb + kk + 3][r] = b.w;
        }
    }
    __syncthreads();
    const int tx = t & 15, ty = t >> 4;
    float acc[4][4] = {};
#pragma unroll 4
    for (int k = 0; k < 128; k++) {
        float4 a4 = *(const float4*)&As[k][ty * 4];
        float4 b4 = *(const float4*)&Bs[k][tx * 4];
        acc[0][0] += a4.x * b4.x; acc[0][1] += a4.x * b4.y; acc[0][2] += a4.x * b4.z; acc[0][3] += a4.x * b4.w;
        acc[1][0] += a4.y * b4.x; acc[1][1] += a4.y * b4.y; acc[1][2] += a4.y * b4.z; acc[1][3] += a4.y * b4.w;
        acc[2][0] += a4.z * b4.x; acc[2][1] += a4.z * b4.y; acc[2][2] += a4.z * b4.z; acc[2][3] += a4.z * b4.w;
        acc[3][0] += a4.w * b4.x; acc[3][1] += a4.w * b4.y; acc[3][2] += a4.w * b4.z; acc[3][3] += a4.w * b4.w;
    }
    float bb[4];
#pragma unroll
    for (int j = 0; j < 4; j++) bb[j] = bi[n0 + tx * 4 + j];
#pragma unroll
    for (int i = 0; i < 4; i++) {
        const int m = m0 + ty * 4 + i;
        ushort4 o;
        o.x = f2bf(acc[i][0] + bb[0]);
        o.y = f2bf(acc[i][1] + bb[1]);
        o.z = f2bf(acc[i][2] + bb[2]);
        o.w = f2bf(acc[i][3] + bb[3]);
        *(ushort4*)(xg + (long)m * 384 + n0 + tx * 4) = o;
    }
}

// ---------------- K2: GRU scan over 32 steps ----------------
// grid 256 (8 seqs/block), block 256: thread = (j = hidden idx 0..127, sp = seq-quad 0/1)
__global__ void k_scan(const u16* __restrict__ xg, const float* __restrict__ Wh,
                       const float* __restrict__ bh, float* __restrict__ tf_out, int dir) {
    __shared__ u16 whl[3][128][128];   // [gate][i][j] = Wh[gate*128+j][i], bf16
    __shared__ float h_lds[128][8];    // [hidden i][seq]
    const int t = threadIdx.x;
    const int j = t & 127, sp = t >> 7;

    if (sp == 0) {
        for (int c = 0; c < 3; c++) {
            const float* src = Wh + (long)(c * 128 + j) * 128;
            for (int i = 0; i < 128; i++) whl[c][i][j] = f2bf(src[i]);
        }
    }
    *(float4*)&((float*)h_lds)[t * 4] = make_float4(0.f, 0.f, 0.f, 0.f);

    const float bh_r = bh[j], bh_z = bh[128 + j], bh_n = bh[256 + j];
    float hreg[4] = {0.f, 0.f, 0.f, 0.f};
    float macc[4] = {0.f, 0.f, 0.f, 0.f};
    const int seq0 = blockIdx.x * 8 + sp * 4;
    __syncthreads();

    for (int tt = 0; tt < 32; tt++) {
        const int tp = dir ? (31 - tt) : tt;
        float xr[4], xz[4], xn[4];
#pragma unroll
        for (int s = 0; s < 4; s++) {
            const u16* p = xg + ((long)(seq0 + s) * 32 + tp) * 384 + j;
            xr[s] = bf2f(p[0]); xz[s] = bf2f(p[128]); xn[s] = bf2f(p[256]);
        }
        float aR[4] = {bh_r, bh_r, bh_r, bh_r};
        float aZ[4] = {bh_z, bh_z, bh_z, bh_z};
        float aN[4] = {bh_n, bh_n, bh_n, bh_n};
#pragma unroll 4
        for (int i = 0; i < 128; i++) {
            float4 hv = *(const float4*)&h_lds[i][sp * 4];
            float wr = bf2f(whl[0][i][j]);
            float wz = bf2f(whl[1][i][j]);
            float wn = bf2f(whl[2][i][j]);
            aR[0] += wr * hv.x; aR[1] += wr * hv.y; aR[2] += wr * hv.z; aR[3] += wr * hv.w;
            aZ[0] += wz * hv.x; aZ[1] += wz * hv.y; aZ[2] += wz * hv.z; aZ[3] += wz * hv.w;
            aN[0] += wn * hv.x; aN[1] += wn * hv.y; aN[2] += wn * hv.z; aN[3] += wn * hv.w;
        }
        __syncthreads();
#pragma unroll
        for (int s = 0; s < 4; s++) {
            float r = sigmoidf(xr[s] + aR[s]);
            float z = sigmoidf(xz[s] + aZ[s]);
            float n = tanhf(xn[s] + r * aN[s]);
            float h = (1.0f - z) * n + z * hreg[s];
            hreg[s] = h;
            macc[s] += h;
        }
        *(float4*)&h_lds[j][sp * 4] = make_float4(hreg[0], hreg[1], hreg[2], hreg[3]);
        __syncthreads();
    }
#pragma unroll
    for (int s = 0; s < 4; s++)
        tf_out[(long)(seq0 + s) * 256 + dir * 128 + j] = macc[s] * (1.0f / 32.0f);
}

// ---------------- K3: text summary scorer (tanh MLP + sigmoid) ----------------
// grid 2048 (one row), block 128
__global__ void k_tsum(const float* __restrict__ tf, const float* __restrict__ W1,
                       const float* __restrict__ b1, const float* __restrict__ w2,
                       const float* __restrict__ b2, float* __restrict__ out) {
    __shared__ float x[256];
    __shared__ float wsum[2];
    const int row = blockIdx.x, t = threadIdx.x;
    x[t] = tf[(long)row * 256 + t];
    x[t + 128] = tf[(long)row * 256 + 128 + t];
    __syncthreads();
    float acc = 0.f;
    const float* w = W1 + (long)t * 256;
#pragma unroll 8
    for (int i = 0; i < 256; i += 4) {
        float4 w4 = *(const float4*)(w + i);
        acc += w4.x * x[i] + w4.y * x[i + 1] + w4.z * x[i + 2] + w4.w * x[i + 3];
    }
    float h = tanhf(acc + b1[t]) * w2[t];
    for (int o = 32; o > 0; o >>= 1) h += __shfl_xor(h, o);
    if ((t & 63) == 0) wsum[t >> 6] = h;
    __syncthreads();
    if (t == 0) out[row] = sigmoidf(wsum[0] + wsum[1] + b2[0]);
}

// ---------------- K4a: convert vf and the three 256x1024 video weight mats to bf16 ----------------
// grid 4864, block 256 (float4 per thread)
__global__ void k_cvt(const float* __restrict__ vf, const float* __restrict__ wa,
                      const float* __restrict__ wb2, const float* __restrict__ wc2,
                      u16* __restrict__ Xb, u16* __restrict__ Wb) {
    long gid = (long)blockIdx.x * 256 + threadIdx.x;
    long i4 = gid * 4;
    float4 v;
    u16* dst;
    if (i4 < 4194304) {
        v = *(const float4*)(vf + i4);
        dst = Xb + i4;
    } else {
        long j = i4 - 4194304;
        dst = Wb + j;
        if (j < 262144) v = *(const float4*)(wa + j);
        else if (j < 524288) v = *(const float4*)(wb2 + (j - 262144));
        else v = *(const float4*)(wc2 + (j - 524288));
    }
    ushort4 o;
    o.x = f2bf(v.x); o.y = f2bf(v.y); o.z = f2bf(v.z); o.w = f2bf(v.w);
    *(ushort4*)dst = o;
}

// ---------------- K4b: G[4096][768] = Xb[4096][1024] @ Wb[768][1024]^T (bf16 MFMA) ----------------
// grid (32, 6), block 256 (4 waves, 2x2 of 64x64), tile 128x128, BK=32
__global__ __launch_bounds__(256) void k_gemmv(const u16* __restrict__ Xb, const u16* __restrict__ Wb,
                                               float* __restrict__ G) {
    __shared__ u16 As[128][40];   // rows padded 32->40 bf16 (80B stride: rows 0..7 hit all 32 banks)
    __shared__ u16 Bs[128][40];
    const int t = threadIdx.x;
    const int m0 = blockIdx.x * 128, n0 = blockIdx.y * 128;
    const int w = t >> 6, l = t & 63;
    const int wr = w >> 1, wc = w & 1;
    const int lrow = l & 15, lk = (l >> 4) * 8;
    f32x4 acc[4][4] = {};
    for (int kk = 0; kk < 32; kk++) {
        const int k0 = kk * 32;
        int4 ra[2], rb[2];
#pragma unroll
        for (int it = 0; it < 2; it++) {
            int e = it * 256 + t;
            int row = e >> 2, c8 = (e & 3) * 8;
            ra[it] = *(const int4*)(Xb + (long)(m0 + row) * 1024 + k0 + c8);
            rb[it] = *(const int4*)(Wb + (long)(n0 + row) * 1024 + k0 + c8);
        }
        __syncthreads();   // prior iteration's fragment reads are done
#pragma unroll
        for (int it = 0; it < 2; it++) {
            int e = it * 256 + t;
            int row = e >> 2, c8 = (e & 3) * 8;
            *(int4*)&As[row][c8] = ra[it];
            *(int4*)&Bs[row][c8] = rb[it];
        }
        __syncthreads();
        short8 af[4], bf[4];
#pragma unroll
        for (int f = 0; f < 4; f++) {
            af[f] = *(const short8*)&As[wr * 64 + f * 16 + lrow][lk];
            bf[f] = *(const short8*)&Bs[wc * 64 + f * 16 + lrow][lk];
        }
#pragma unroll
        for (int fm = 0; fm < 4; fm++)
#pragma unroll
            for (int fn = 0; fn < 4; fn++)
                acc[fm][fn] = __builtin_amdgcn_mfma_f32_16x16x32_bf16(af[fm], bf[fn], acc[fm][fn], 0, 0, 0);
    }
    const int orow = (l >> 4) * 4, ocol = l & 15;
#pragma unroll
    for (int fm = 0; fm < 4; fm++)
#pragma unroll
        for (int fn = 0; fn < 4; fn++) {
            long base = (long)(m0 + wr * 64 + fm * 16 + orow) * 768 + n0 + wc * 64 + fn * 16 + ocol;
#pragma unroll
            for (int r = 0; r < 4; r++)
                G[base + (long)r * 768] = acc[fm][fn][r];
        }
}

// ---------------- K4c: video epilogue — scorer layer-2 + scaled V projection ----------------
// grid 1024, block 256 (wave per row, 4096 rows)
__global__ void k_vepi(const float* __restrict__ G,
                       const float* __restrict__ bv, const float* __restrict__ w2v, const float* __restrict__ b2v,
                       const float* __restrict__ bt, const float* __restrict__ w2t, const float* __restrict__ b2t,
                       const float* __restrict__ vpb,
                       float* __restrict__ V, float* __restrict__ vsp, float* __restrict__ vseg) {
    const int r = blockIdx.x * 4 + (threadIdx.x >> 6);
    const int lane = threadIdx.x & 63;
    const float* g = G + (long)r * 768;
    float s1 = 0.f, s2 = 0.f;
#pragma unroll
    for (int c = 0; c < 4; c++) {
        int h = lane + c * 64;
        s1 += tanhf(g[h] + bv[h]) * w2v[h];
        s2 += fmaxf(g[256 + h] + bt[h], 0.f) * w2t[h];
    }
    for (int o = 32; o > 0; o >>= 1) { s1 += __shfl_xor(s1, o); s2 += __shfl_xor(s2, o); }
    float p = sigmoidf(s1 + b2v[0]);
    if (lane == 0) {
        vsp[r] = p;
        vseg[r] = sigmoidf(s2 + b2t[0]);
    }
#pragma unroll
    for (int c = 0; c < 4; c++) {
        int a = lane + c * 64;
        V[(long)r * 256 + a] = vpb[a] + p * g[512 + a];
    }
}

// ---------------- K5a: E_proj = (tf * tsp) @ tproj_W^T + b ----------------
// grid 256 (8 rows/block), block 256 (thread = out col)
__global__ void k_eproj(const float* __restrict__ tf, const float* __restrict__ tsp,
                        const float* __restrict__ W, const float* __restrict__ b,
                        float* __restrict__ E) {
    __shared__ float x[8][256];
    __shared__ float p[8];
    const int r0 = blockIdx.x * 8, t = threadIdx.x;
    const float4* src = (const float4*)(tf + (long)r0 * 256);
    for (int i = t; i < 512; i += 256) ((float4*)&x[0][0])[i] = src[i];
    if (t < 8) p[t] = tsp[r0 + t];
    __syncthreads();
    float acc[8] = {};
    const float* w = W + (long)t * 256;
    for (int i = 0; i < 256; i += 4) {
        float4 w4 = *(const float4*)(w + i);
#pragma unroll
        for (int r = 0; r < 8; r++) {
            float4 x4 = *(const float4*)&x[r][i];
            acc[r] += w4.x * x4.x + w4.y * x4.y + w4.z * x4.z + w4.w * x4.w;
        }
    }
    const float bb = b[t];
#pragma unroll
    for (int r = 0; r < 8; r++) E[(long)(r0 + r) * 256 + t] = bb + p[r] * acc[r];
}

// ---------------- K6: row L2-normalize E (2048 rows) and V (4096 rows) in place ----------------
// grid 1536, block 256 (wave per row)
__global__ void k_norm(float* __restrict__ E, float* __restrict__ V) {
    const int w = threadIdx.x >> 6, lane = threadIdx.x & 63;
    const int row = blockIdx.x * 4 + w;
    float* ptr = (row < 2048) ? (E + (long)row * 256) : (V + (long)(row - 2048) * 256);
    float4 v = ((float4*)ptr)[lane];
    float s = v.x * v.x + v.y * v.y + v.z * v.z + v.w * v.w;
    for (int o = 32; o > 0; o >>= 1) s += __shfl_xor(s, o);
    float sc = 1.0f / (sqrtf(s) + 1e-12f);
    v.x *= sc; v.y *= sc; v.z *= sc; v.w *= sc;
    ((float4*)ptr)[lane] = v;
}

// ---------------- K7: C = 1 - En . Vn^T  and Km = exp(-C/reg) ----------------
// grid (16, 8), block 256 (thread = m)
__global__ void k_cost(const float* __restrict__ E, const float* __restrict__ V,
                       float* __restrict__ C, float* __restrict__ Km) {
    __shared__ float en[16][256];
    const int b = blockIdx.x, k0 = blockIdx.y * 16, t = threadIdx.x;
    const float4* esrc = (const float4*)(E + ((long)b * 128 + k0) * 256);
    for (int i = t; i < 1024; i += 256) ((float4*)&en[0][0])[i] = esrc[i];
    __syncthreads();
    float acc[16] = {};
    const float* vrow = V + ((long)b * 256 + t) * 256;
    for (int i = 0; i < 256; i += 4) {
        float4 v4 = *(const float4*)(vrow + i);
#pragma unroll
        for (int k = 0; k < 16; k++) {
            float4 e4 = *(const float4*)&en[k][i];
            acc[k] += e4.x * v4.x + e4.y * v4.y + e4.z * v4.z + e4.w * v4.w;
        }
    }
#pragma unroll
    for (int k = 0; k < 16; k++) {
        float c = 1.0f - acc[k];
        long idx = (long)b * 32768 + (long)(k0 + k) * 256 + t;
        C[idx] = c;
        Km[idx] = expf(-20.0f * c);
    }
}

// ---------------- K8: Sinkhorn iterations + T + loss ----------------
// grid 16 (one per batch), block 512
__global__ void k_sink(const float* __restrict__ C, const float* __restrict__ Km,
                       float* __restrict__ T, float* __restrict__ loss) {
    __shared__ float u[128];
    __shared__ float v[256];
    __shared__ float red[8];
    const int b = blockIdx.x, t = threadIdx.x;
    const float* Kb = Km + (long)b * 32768;
    const float* Cb = C + (long)b * 32768;
    if (t < 128) u[t] = 1.0f / 128.0f;
    if (t < 256) v[t] = 1.0f / 256.0f;
    __syncthreads();
    for (int it = 0; it < 10; it++) {
        {   // u = mu / (Km @ v + 1e-8);  t = k*4 + q, q covers 64 m's
            const int k = t >> 2, q = t & 3;
            const float* kr = Kb + (long)k * 256 + q * 64;
            float s = 0.f;
#pragma unroll 4
            for (int m = 0; m < 64; m += 4) {
                float4 k4 = *(const float4*)(kr + m);
                float4 vv = *(const float4*)&v[q * 64 + m];
                s += k4.x * vv.x + k4.y * vv.y + k4.z * vv.z + k4.w * vv.w;
            }
            s += __shfl_xor(s, 1);
            s += __shfl_xor(s, 2);
            float un = (1.0f / 128.0f) / (s + 1e-8f);
            u[k] = un;
            __syncthreads();
        }
        {   // v = nu / (Km^T @ u + 1e-8);  t = m*2 + q, q covers 64 k's
            const int m = t >> 1, q = t & 1;
            float s = 0.f;
            for (int k = 0; k < 64; k += 4) {
                float4 u4 = *(const float4*)&u[q * 64 + k];
                s += Kb[(long)(q * 64 + k + 0) * 256 + m] * u4.x;
                s += Kb[(long)(q * 64 + k + 1) * 256 + m] * u4.y;
                s += Kb[(long)(q * 64 + k + 2) * 256 + m] * u4.z;
                s += Kb[(long)(q * 64 + k + 3) * 256 + m] * u4.w;
            }
            s += __shfl_xor(s, 1);
            float vn = (1.0f / 256.0f) / (s + 1e-8f);
            v[m] = vn;
            __syncthreads();
        }
    }
    float part = 0.f;
    for (int i = 0; i < 64; i++) {
        int idx = i * 512 + t;
        int k = idx >> 8, m = idx & 255;
        float tv = u[k] * Kb[idx] * v[m];
        T[(long)b * 32768 + idx] = tv;
        part += tv * Cb[idx];
    }
    for (int o = 32; o > 0; o >>= 1) part += __shfl_xor(part, o);
    if ((t & 63) == 0) red[t >> 6] = part;
    __syncthreads();
    if (t == 0) {
        float s = red[0] + red[1] + red[2] + red[3] + red[4] + red[5] + red[6] + red[7];
        atomicAdd(loss, s * (1.0f / 16.0f));
    }
}

extern "C" void kernel_launch(void* const* d_in, const int* in_sizes, int n_in,
                              void* d_out, int out_size, void* d_ws, size_t ws_size,
                              hipStream_t stream) {
    const int*   ids  = (const int*)d_in[0];
    // d_in[1] = attention_mask (all ones, unused by the reference math)
    const float* vf   = (const float*)d_in[2];
    const float* emb  = (const float*)d_in[3];
    const float* WiF  = (const float*)d_in[4];
    const float* WhF  = (const float*)d_in[5];
    const float* biF  = (const float*)d_in[6];
    const float* bhF  = (const float*)d_in[7];
    const float* WiB  = (const float*)d_in[8];
    const float* WhB  = (const float*)d_in[9];
    const float* biB  = (const float*)d_in[10];
    const float* bhB  = (const float*)d_in[11];
    const float* tpW  = (const float*)d_in[12];
    const float* tpb  = (const float*)d_in[13];
    const float* vpW  = (const float*)d_in[14];
    const float* vpb  = (const float*)d_in[15];
    const float* tsW1 = (const float*)d_in[16];
    const float* tsb1 = (const float*)d_in[17];
    const float* tsw2 = (const float*)d_in[18];
    const float* tsb2 = (const float*)d_in[19];
    const float* vsW1 = (const float*)d_in[20];
    const float* vsb1 = (const float*)d_in[21];
    const float* vsw2 = (const float*)d_in[22];
    const float* vsb2 = (const float*)d_in[23];
    const float* vtW1 = (const float*)d_in[24];
    const float* vtb1 = (const float*)d_in[25];
    const float* vtw2 = (const float*)d_in[26];
    const float* vtb2 = (const float*)d_in[27];
    float* out = (float*)d_out;

    // workspace layout (bytes):
    //   XG  bf16 [2048][32][384]  : 0           .. 50,331,648   (dead after 2nd k_scan)
    //     -- video-path buffers overlay the XG region after the scans: --
    //     Xb bf16 [4096][1024]    : 0           ..  8,388,608
    //     Wb bf16 [768][1024]     : 8,388,608   ..  9,961,472
    //     G  f32  [4096][768]     : 9,961,472   .. 22,544,384
    //   E   f32  [2048][256]      : 50,331,648  ..  +2,097,152
    //   V   f32  [4096][256]      : 52,428,800  ..  +4,194,304
    //   C   f32  [16][128][256]   : 56,623,104  ..  +2,097,152
    //   Km  f32  [16][128][256]   : 58,720,256  ..  +2,097,152   (total 60,817,408)
    char* ws = (char*)d_ws;
    u16*   XG = (u16*)ws;
    u16*   Xb = (u16*)ws;
    u16*   Wb = (u16*)(ws + 8388608);
    float* G  = (float*)(ws + 9961472);
    float* E  = (float*)(ws + 50331648);
    float* V  = (float*)(ws + 52428800);
    float* C  = (float*)(ws + 56623104);
    float* Km = (float*)(ws + 58720256);

    float* tf   = out + 2048;      // text_features (16,128,256)
    float* vseg = out + 526336;    // video_seg_probs (16,256)
    float* tsp  = out + 530432;    // text_summ_probs (16,128)
    float* vsp  = out + 532480;    // video_summ_probs (16,256)
    float* loss = out + 536576;    // ot_loss scalar
    float* T    = out + 536577;    // T (16,128,256)

    k_zero<<<8, 256, 0, stream>>>(out);

    // text path: forward + backward GRU (XG buffer reused across dirs)
    k_xg<<<dim3(1024, 6), 256, 0, stream>>>(ids, emb, WiF, biF, XG);
    k_scan<<<256, 256, 0, stream>>>(XG, WhF, bhF, tf, 0);
    k_xg<<<dim3(1024, 6), 256, 0, stream>>>(ids, emb, WiB, biB, XG);
    k_scan<<<256, 256, 0, stream>>>(XG, WhB, bhB, tf, 1);

    // video path (after scans: overlays XG region): one MFMA GEMM for both scorers + projection
    k_cvt<<<4864, 256, 0, stream>>>(vf, vsW1, vtW1, vpW, Xb, Wb);
    k_gemmv<<<dim3(32, 6), 256, 0, stream>>>(Xb, Wb, G);
    k_vepi<<<1024, 256, 0, stream>>>(G, vsb1, vsw2, vsb2, vtb1, vtw2, vtb2, vpb, V, vsp, vseg);

    k_tsum<<<2048, 128, 0, stream>>>(tf, tsW1, tsb1, tsw2, tsb2, tsp);
    k_eproj<<<256, 256, 0, stream>>>(tf, tsp, tpW, tpb, E);
    k_norm<<<1536, 256, 0, stream>>>(E, V);
    k_cost<<<dim3(16, 8), 256, 0, stream>>>(E, V, C, Km);
    k_sink<<<16, 512, 0, stream>>>(C, Km, T, loss);
}

// Round 8
// 572.731 us; speedup vs baseline: 2.0703x; 1.6266x over previous
//
#include <hip/hip_runtime.h>
#include <hip/hip_bf16.h>

typedef unsigned short u16;
typedef __attribute__((ext_vector_type(8))) short short8;
typedef __attribute__((ext_vector_type(4))) float f32x4;

static __device__ __forceinline__ float bf2f(u16 x) {
    unsigned int u = ((unsigned int)x) << 16;
    return __uint_as_float(u);
}
static __device__ __forceinline__ u16 f2bf(float f) {
    unsigned int u = __float_as_uint(f);
    unsigned int r = (u + 0x7fffu + ((u >> 16) & 1u)) >> 16;
    return (u16)r;
}
static __device__ __forceinline__ float sigmoidf(float x) {
    return 1.0f / (1.0f + expf(-x));
}

// ---------------- K0: zero text_seg_probs + loss slot ----------------
__global__ void k_zero(float* __restrict__ out) {
    int t = blockIdx.x * 256 + threadIdx.x;
    if (t < 2048) out[t] = 0.0f;
    if (t == 0) out[536576] = 0.0f;
}

// ---------------- K1a: convert emb table + WiF + WiB to bf16 ----------------
// emb: 30522*128 = 3,906,816 f32; WiF/WiB: 384*128 = 49,152 f32 each.
// grid 3912, block 256 (float4 per thread, bounds-checked).
__global__ void k_cvte(const float* __restrict__ emb, const float* __restrict__ WiF,
                       const float* __restrict__ WiB, u16* __restrict__ dst) {
    long i4 = ((long)blockIdx.x * 256 + threadIdx.x) * 4;
    if (i4 >= 4005120) return;
    float4 v;
    if (i4 < 3906816) v = *(const float4*)(emb + i4);
    else if (i4 < 3955968) v = *(const float4*)(WiF + (i4 - 3906816));
    else v = *(const float4*)(WiB + (i4 - 3955968));
    ushort4 o;
    o.x = f2bf(v.x); o.y = f2bf(v.y); o.z = f2bf(v.z); o.w = f2bf(v.w);
    *(ushort4*)(dst + i4) = o;
}

// ---------------- K1b: xg = gather(embb)[65536,128] @ Wib^T[128,384] + bi -> bf16 (MFMA) ----------------
// Structural clone of the hardware-validated k_gemmv (same staging, fragments, C-layout).
// grid (512, 3), block 256 (4 waves, 2x2 of 64x64), tile 128x128, BK=32 x 4 steps.
// Novel vs k_gemmv: A rows gathered via ids[]; epilogue adds bi and stores bf16.
__global__ __launch_bounds__(256) void k_xg2(const int* __restrict__ ids, const u16* __restrict__ embb,
                                             const u16* __restrict__ Wib, const float* __restrict__ bi,
                                             u16* __restrict__ xg) {
    __shared__ u16 As[128][40];   // rows padded 32->40 bf16
    __shared__ u16 Bs[128][40];
    const int t = threadIdx.x;
    const int m0 = blockIdx.x * 128, n0 = blockIdx.y * 128;
    const int w = t >> 6, l = t & 63;
    const int wr = w >> 1, wc = w & 1;
    const int lrow = l & 15, lk = (l >> 4) * 8;
    f32x4 acc[4][4] = {};
#pragma unroll
    for (int kk = 0; kk < 4; kk++) {
        const int k0 = kk * 32;
        int4 ra[2], rb[2];
#pragma unroll
        for (int it = 0; it < 2; it++) {
            int e = it * 256 + t;
            int row = e >> 2, c8 = (e & 3) * 8;
            int id = ids[m0 + row];
            ra[it] = *(const int4*)(embb + (long)id * 128 + k0 + c8);
            rb[it] = *(const int4*)(Wib + (long)(n0 + row) * 128 + k0 + c8);
        }
        __syncthreads();   // prior iteration's fragment reads are done
#pragma unroll
        for (int it = 0; it < 2; it++) {
            int e = it * 256 + t;
            int row = e >> 2, c8 = (e & 3) * 8;
            *(int4*)&As[row][c8] = ra[it];
            *(int4*)&Bs[row][c8] = rb[it];
        }
        __syncthreads();
        short8 af[4], bf[4];
#pragma unroll
        for (int f = 0; f < 4; f++) {
            af[f] = *(const short8*)&As[wr * 64 + f * 16 + lrow][lk];
            bf[f] = *(const short8*)&Bs[wc * 64 + f * 16 + lrow][lk];
        }
#pragma unroll
        for (int fm = 0; fm < 4; fm++)
#pragma unroll
            for (int fn = 0; fn < 4; fn++)
                acc[fm][fn] = __builtin_amdgcn_mfma_f32_16x16x32_bf16(af[fm], bf[fn], acc[fm][fn], 0, 0, 0);
    }
    const int orow = (l >> 4) * 4, ocol = l & 15;
#pragma unroll
    for (int fm = 0; fm < 4; fm++)
#pragma unroll
        for (int fn = 0; fn < 4; fn++) {
            const int col = n0 + wc * 64 + fn * 16 + ocol;
            const float bbv = bi[col];
            const int row0 = m0 + wr * 64 + fm * 16 + orow;
#pragma unroll
            for (int r = 0; r < 4; r++)
                xg[(long)(row0 + r) * 384 + col] = f2bf(acc[fm][fn][r] + bbv);
        }
}

// ---------------- K2: MFMA GRU scan over 32 steps ----------------
// grid 256 (8 seqs/block, padded to M=16), block 256 (4 waves).
// Wave w owns hidden cols [w*32, w*32+32) x 3 gates = 6 MFMA N-tiles.
// Wh slice lives in 24 B-fragments (96 VGPRs) per wave; h double-buffers
// through a tiny LDS tile (8.7 KB total, vs 100 KB before).
__global__ __launch_bounds__(256) void k_scan2(const u16* __restrict__ xg,
                                               const float* __restrict__ Wh,
                                               const float* __restrict__ bh,
                                               float* __restrict__ tf_out, int dir) {
    __shared__ u16 hbuf[2][16][136];   // [buf][seq-row m][hidden k], pad 128->136
    const int t = threadIdx.x;
    const int w = t >> 6, l = t & 63;
    const int lr = l & 15, hi = l >> 4;
    const int seq0 = blockIdx.x * 8;

    // --- preload B fragments: breg[gate][h2][ktile], layout validated by k_gemmv ---
    short8 breg[3][2][4];
    float bb[3][2];
#pragma unroll
    for (int g = 0; g < 3; g++)
#pragma unroll
        for (int h2 = 0; h2 < 2; h2++) {
            const int ncol = g * 128 + w * 32 + h2 * 16 + lr;
            const float* wrow = Wh + (long)ncol * 128;
            bb[g][h2] = bh[ncol];
#pragma unroll
            for (int q = 0; q < 4; q++) {
                float4 a = *(const float4*)(wrow + q * 32 + hi * 8);
                float4 b = *(const float4*)(wrow + q * 32 + hi * 8 + 4);
                short8 s;
                s[0] = f2bf(a.x); s[1] = f2bf(a.y); s[2] = f2bf(a.z); s[3] = f2bf(a.w);
                s[4] = f2bf(b.x); s[5] = f2bf(b.y); s[6] = f2bf(b.z); s[7] = f2bf(b.w);
                breg[g][h2][q] = s;
            }
        }

    // zero both h buffers (rows 8..15 stay zero forever)
    for (int i = t; i < 2176; i += 256) ((int*)hbuf)[i] = 0;

    float hreg[2][4] = {};   // [h2][reg] running h (f32), valid when hi<2
    float macc[2][4] = {};
    __syncthreads();

    for (int tt = 0; tt < 32; tt++) {
        const int tp = dir ? (31 - tt) : tt;
        const int cur = tt & 1;

        // xg in C-fragment layout (issue early to hide latency under MFMA)
        float xv[3][2][4];
        if (hi < 2) {
#pragma unroll
            for (int g = 0; g < 3; g++)
#pragma unroll
                for (int h2 = 0; h2 < 2; h2++)
#pragma unroll
                    for (int r = 0; r < 4; r++) {
                        const int m = hi * 4 + r;
                        xv[g][h2][r] = bf2f(xg[((long)(seq0 + m) * 32 + tp) * 384
                                               + g * 128 + w * 32 + h2 * 16 + lr]);
                    }
        }

        // A fragments from current h buffer: lane holds row lr, k = q*32+hi*8..+8
        short8 af[4];
#pragma unroll
        for (int q = 0; q < 4; q++)
            af[q] = *(const short8*)&hbuf[cur][lr][q * 32 + hi * 8];

        // hg[m][n] = sum_k h[m][k] * Wh[n][k]
        f32x4 acc[3][2];
#pragma unroll
        for (int g = 0; g < 3; g++)
#pragma unroll
            for (int h2 = 0; h2 < 2; h2++) {
                f32x4 a = {0.f, 0.f, 0.f, 0.f};
#pragma unroll
                for (int q = 0; q < 4; q++)
                    a = __builtin_amdgcn_mfma_f32_16x16x32_bf16(af[q], breg[g][h2][q], a, 0, 0, 0);
                acc[g][h2] = a;
            }

        // GRU gate update; write next h buffer
        if (hi < 2) {
#pragma unroll
            for (int h2 = 0; h2 < 2; h2++)
#pragma unroll
                for (int r = 0; r < 4; r++) {
                    float rg = sigmoidf(xv[0][h2][r] + acc[0][h2][r] + bb[0][h2]);
                    float zg = sigmoidf(xv[1][h2][r] + acc[1][h2][r] + bb[1][h2]);
                    float ng = tanhf(xv[2][h2][r] + rg * (acc[2][h2][r] + bb[2][h2]));
                    float h = (1.0f - zg) * ng + zg * hreg[h2][r];
                    hreg[h2][r] = h;
                    macc[h2][r] += h;
                    hbuf[cur ^ 1][hi * 4 + r][w * 32 + h2 * 16 + lr] = f2bf(h);
                }
        }
        __syncthreads();
    }

    if (hi < 2) {
#pragma unroll
        for (int h2 = 0; h2 < 2; h2++)
#pragma unroll
            for (int r = 0; r < 4; r++)
                tf_out[(long)(seq0 + hi * 4 + r) * 256 + dir * 128 + w * 32 + h2 * 16 + lr]
                    = macc[h2][r] * (1.0f / 32.0f);
    }
}

// ---------------- K3: text summary scorer (tanh MLP + sigmoid) ----------------
// grid 2048 (one row), block 128
__global__ void k_tsum(const float* __restrict__ tf, const float* __restrict__ W1,
                       const float* __restrict__ b1, const float* __restrict__ w2,
                       const float* __restrict__ b2, float* __restrict__ out) {
    __shared__ float x[256];
    __shared__ float wsum[2];
    const int row = blockIdx.x, t = threadIdx.x;
    x[t] = tf[(long)row * 256 + t];
    x[t + 128] = tf[(long)row * 256 + 128 + t];
    __syncthreads();
    float acc = 0.f;
    const float* w = W1 + (long)t * 256;
#pragma unroll 8
    for (int i = 0; i < 256; i += 4) {
        float4 w4 = *(const float4*)(w + i);
        acc += w4.x * x[i] + w4.y * x[i + 1] + w4.z * x[i + 2] + w4.w * x[i + 3];
    }
    float h = tanhf(acc + b1[t]) * w2[t];
    for (int o = 32; o > 0; o >>= 1) h += __shfl_xor(h, o);
    if ((t & 63) == 0) wsum[t >> 6] = h;
    __syncthreads();
    if (t == 0) out[row] = sigmoidf(wsum[0] + wsum[1] + b2[0]);
}

// ---------------- K4a: convert vf and the three 256x1024 video weight mats to bf16 ----------------
// grid 4864, block 256 (float4 per thread)
__global__ void k_cvt(const float* __restrict__ vf, const float* __restrict__ wa,
                      const float* __restrict__ wb2, const float* __restrict__ wc2,
                      u16* __restrict__ Xb, u16* __restrict__ Wb) {
    long gid = (long)blockIdx.x * 256 + threadIdx.x;
    long i4 = gid * 4;
    float4 v;
    u16* dst;
    if (i4 < 4194304) {
        v = *(const float4*)(vf + i4);
        dst = Xb + i4;
    } else {
        long j = i4 - 4194304;
        dst = Wb + j;
        if (j < 262144) v = *(const float4*)(wa + j);
        else if (j < 524288) v = *(const float4*)(wb2 + (j - 262144));
        else v = *(const float4*)(wc2 + (j - 524288));
    }
    ushort4 o;
    o.x = f2bf(v.x); o.y = f2bf(v.y); o.z = f2bf(v.z); o.w = f2bf(v.w);
    *(ushort4*)dst = o;
}

// ---------------- K4b: G[4096][768] = Xb[4096][1024] @ Wb[768][1024]^T (bf16 MFMA) ----------------
// grid (32, 6), block 256 (4 waves, 2x2 of 64x64), tile 128x128, BK=32
__global__ __launch_bounds__(256) void k_gemmv(const u16* __restrict__ Xb, const u16* __restrict__ Wb,
                                               float* __restrict__ G) {
    __shared__ u16 As[128][40];   // rows padded 32->40 bf16 (80B stride: rows 0..7 hit all 32 banks)
    __shared__ u16 Bs[128][40];
    const int t = threadIdx.x;
    const int m0 = blockIdx.x * 128, n0 = blockIdx.y * 128;
    const int w = t >> 6, l = t & 63;
    const int wr = w >> 1, wc = w & 1;
    const int lrow = l & 15, lk = (l >> 4) * 8;
    f32x4 acc[4][4] = {};
    for (int kk = 0; kk < 32; kk++) {
        const int k0 = kk * 32;
        int4 ra[2], rb[2];
#pragma unroll
        for (int it = 0; it < 2; it++) {
            int e = it * 256 + t;
            int row = e >> 2, c8 = (e & 3) * 8;
            ra[it] = *(const int4*)(Xb + (long)(m0 + row) * 1024 + k0 + c8);
            rb[it] = *(const int4*)(Wb + (long)(n0 + row) * 1024 + k0 + c8);
        }
        __syncthreads();   // prior iteration's fragment reads are done
#pragma unroll
        for (int it = 0; it < 2; it++) {
            int e = it * 256 + t;
            int row = e >> 2, c8 = (e & 3) * 8;
            *(int4*)&As[row][c8] = ra[it];
            *(int4*)&Bs[row][c8] = rb[it];
        }
        __syncthreads();
        short8 af[4], bf[4];
#pragma unroll
        for (int f = 0; f < 4; f++) {
            af[f] = *(const short8*)&As[wr * 64 + f * 16 + lrow][lk];
            bf[f] = *(const short8*)&Bs[wc * 64 + f * 16 + lrow][lk];
        }
#pragma unroll
        for (int fm = 0; fm < 4; fm++)
#pragma unroll
            for (int fn = 0; fn < 4; fn++)
                acc[fm][fn] = __builtin_amdgcn_mfma_f32_16x16x32_bf16(af[fm], bf[fn], acc[fm][fn], 0, 0, 0);
    }
    const int orow = (l >> 4) * 4, ocol = l & 15;
#pragma unroll
    for (int fm = 0; fm < 4; fm++)
#pragma unroll
        for (int fn = 0; fn < 4; fn++) {
            long base = (long)(m0 + wr * 64 + fm * 16 + orow) * 768 + n0 + wc * 64 + fn * 16 + ocol;
#pragma unroll
            for (int r = 0; r < 4; r++)
                G[base + (long)r * 768] = acc[fm][fn][r];
        }
}

// ---------------- K4c: video epilogue — scorer layer-2 + scaled V projection ----------------
// grid 1024, block 256 (wave per row, 4096 rows)
__global__ void k_vepi(const float* __restrict__ G,
                       const float* __restrict__ bv, const float* __restrict__ w2v, const float* __restrict__ b2v,
                       const float* __restrict__ bt, const float* __restrict__ w2t, const float* __restrict__ b2t,
                       const float* __restrict__ vpb,
                       float* __restrict__ V, float* __restrict__ vsp, float* __restrict__ vseg) {
    const int r = blockIdx.x * 4 + (threadIdx.x >> 6);
    const int lane = threadIdx.x & 63;
    const float* g = G + (long)r * 768;
    float s1 = 0.f, s2 = 0.f;
#pragma unroll
    for (int c = 0; c < 4; c++) {
        int h = lane + c * 64;
        s1 += tanhf(g[h] + bv[h]) * w2v[h];
        s2 += fmaxf(g[256 + h] + bt[h], 0.0f) * w2t[h];
    }
    for (int o = 32; o > 0; o >>= 1) { s1 += __shfl_xor(s1, o); s2 += __shfl_xor(s2, o); }
    float p = sigmoidf(s1 + b2v[0]);
    if (lane == 0) {
        vsp[r] = p;
        vseg[r] = sigmoidf(s2 + b2t[0]);
    }
#pragma unroll
    for (int c = 0; c < 4; c++) {
        int a = lane + c * 64;
        V[(long)r * 256 + a] = vpb[a] + p * g[512 + a];
    }
}

// ---------------- K5a: E_proj = (tf * tsp) @ tproj_W^T + b ----------------
// grid 256 (8 rows/block), block 256 (thread = out col)
__global__ void k_eproj(const float* __restrict__ tf, const float* __restrict__ tsp,
                        const float* __restrict__ W, const float* __restrict__ b,
                        float* __restrict__ E) {
    __shared__ float x[8][256];
    __shared__ float p[8];
    const int r0 = blockIdx.x * 8, t = threadIdx.x;
    const float4* src = (const float4*)(tf + (long)r0 * 256);
    for (int i = t; i < 512; i += 256) ((float4*)&x[0][0])[i] = src[i];
    if (t < 8) p[t] = tsp[r0 + t];
    __syncthreads();
    float acc[8] = {};
    const float* w = W + (long)t * 256;
    for (int i = 0; i < 256; i += 4) {
        float4 w4 = *(const float4*)(w + i);
#pragma unroll
        for (int r = 0; r < 8; r++) {
            float4 x4 = *(const float4*)&x[r][i];
            acc[r] += w4.x * x4.x + w4.y * x4.y + w4.z * x4.z + w4.w * x4.w;
        }
    }
    const float bb = b[t];
#pragma unroll
    for (int r = 0; r < 8; r++) E[(long)(r0 + r) * 256 + t] = bb + p[r] * acc[r];
}

// ---------------- K6: row L2-normalize E (2048 rows) and V (4096 rows) in place ----------------
// grid 1536, block 256 (wave per row)
__global__ void k_norm(float* __restrict__ E, float* __restrict__ V) {
    const int w = threadIdx.x >> 6, lane = threadIdx.x & 63;
    const int row = blockIdx.x * 4 + w;
    float* ptr = (row < 2048) ? (E + (long)row * 256) : (V + (long)(row - 2048) * 256);
    float4 v = ((float4*)ptr)[lane];
    float s = v.x * v.x + v.y * v.y + v.z * v.z + v.w * v.w;
    for (int o = 32; o > 0; o >>= 1) s += __shfl_xor(s, o);
    float sc = 1.0f / (sqrtf(s) + 1e-12f);
    v.x *= sc; v.y *= sc; v.z *= sc; v.w *= sc;
    ((float4*)ptr)[lane] = v;
}

// ---------------- K7: C = 1 - En . Vn^T  and Km = exp(-C/reg) ----------------
// grid (16, 8), block 256 (thread = m)
__global__ void k_cost(const float* __restrict__ E, const float* __restrict__ V,
                       float* __restrict__ C, float* __restrict__ Km) {
    __shared__ float en[16][256];
    const int b = blockIdx.x, k0 = blockIdx.y * 16, t = threadIdx.x;
    const float4* esrc = (const float4*)(E + ((long)b * 128 + k0) * 256);
    for (int i = t; i < 1024; i += 256) ((float4*)&en[0][0])[i] = esrc[i];
    __syncthreads();
    float acc[16] = {};
    const float* vrow = V + ((long)b * 256 + t) * 256;
    for (int i = 0; i < 256; i += 4) {
        float4 v4 = *(const float4*)(vrow + i);
#pragma unroll
        for (int k = 0; k < 16; k++) {
            float4 e4 = *(const float4*)&en[k][i];
            acc[k] += e4.x * v4.x + e4.y * v4.y + e4.z * v4.z + e4.w * v4.w;
        }
    }
#pragma unroll
    for (int k = 0; k < 16; k++) {
        float c = 1.0f - acc[k];
        long idx = (long)b * 32768 + (long)(k0 + k) * 256 + t;
        C[idx] = c;
        Km[idx] = expf(-20.0f * c);
    }
}

// ---------------- K8: Sinkhorn iterations + T + loss ----------------
// grid 16 (one per batch), block 512
__global__ void k_sink(const float* __restrict__ C, const float* __restrict__ Km,
                       float* __restrict__ T, float* __restrict__ loss) {
    __shared__ float u[128];
    __shared__ float v[256];
    __shared__ float red[8];
    const int b = blockIdx.x, t = threadIdx.x;
    const float* Kb = Km + (long)b * 32768;
    const float* Cb = C + (long)b * 32768;
    if (t < 128) u[t] = 1.0f / 128.0f;
    if (t < 256) v[t] = 1.0f / 256.0f;
    __syncthreads();
    for (int it = 0; it < 10; it++) {
        {   // u = mu / (Km @ v + 1e-8);  t = k*4 + q, q covers 64 m's
            const int k = t >> 2, q = t & 3;
            const float* kr = Kb + (long)k * 256 + q * 64;
            float s = 0.f;
#pragma unroll 4
            for (int m = 0; m < 64; m += 4) {
                float4 k4 = *(const float4*)(kr + m);
                float4 vv = *(const float4*)&v[q * 64 + m];
                s += k4.x * vv.x + k4.y * vv.y + k4.z * vv.z + k4.w * vv.w;
            }
            s += __shfl_xor(s, 1);
            s += __shfl_xor(s, 2);
            float un = (1.0f / 128.0f) / (s + 1e-8f);
            u[k] = un;
            __syncthreads();
        }
        {   // v = nu / (Km^T @ u + 1e-8);  t = m*2 + q, q covers 64 k's
            const int m = t >> 1, q = t & 1;
            float s = 0.f;
            for (int k = 0; k < 64; k += 4) {
                float4 u4 = *(const float4*)&u[q * 64 + k];
                s += Kb[(long)(q * 64 + k + 0) * 256 + m] * u4.x;
                s += Kb[(long)(q * 64 + k + 1) * 256 + m] * u4.y;
                s += Kb[(long)(q * 64 + k + 2) * 256 + m] * u4.z;
                s += Kb[(long)(q * 64 + k + 3) * 256 + m] * u4.w;
            }
            s += __shfl_xor(s, 1);
            float vn = (1.0f / 256.0f) / (s + 1e-8f);
            v[m] = vn;
            __syncthreads();
        }
    }
    float part = 0.f;
    for (int i = 0; i < 64; i++) {
        int idx = i * 512 + t;
        int k = idx >> 8, m = idx & 255;
        float tv = u[k] * Kb[idx] * v[m];
        T[(long)b * 32768 + idx] = tv;
        part += tv * Cb[idx];
    }
    for (int o = 32; o > 0; o >>= 1) part += __shfl_xor(part, o);
    if ((t & 63) == 0) red[t >> 6] = part;
    __syncthreads();
    if (t == 0) {
        float s = red[0] + red[1] + red[2] + red[3] + red[4] + red[5] + red[6] + red[7];
        atomicAdd(loss, s * (1.0f / 16.0f));
    }
}

extern "C" void kernel_launch(void* const* d_in, const int* in_sizes, int n_in,
                              void* d_out, int out_size, void* d_ws, size_t ws_size,
                              hipStream_t stream) {
    const int*   ids  = (const int*)d_in[0];
    // d_in[1] = attention_mask (all ones, unused by the reference math)
    const float* vf   = (const float*)d_in[2];
    const float* emb  = (const float*)d_in[3];
    const float* WiF  = (const float*)d_in[4];
    const float* WhF  = (const float*)d_in[5];
    const float* biF  = (const float*)d_in[6];
    const float* bhF  = (const float*)d_in[7];
    const float* WiB  = (const float*)d_in[8];
    const float* WhB  = (const float*)d_in[9];
    const float* biB  = (const float*)d_in[10];
    const float* bhB  = (const float*)d_in[11];
    const float* tpW  = (const float*)d_in[12];
    const float* tpb  = (const float*)d_in[13];
    const float* vpW  = (const float*)d_in[14];
    const float* vpb  = (const float*)d_in[15];
    const float* tsW1 = (const float*)d_in[16];
    const float* tsb1 = (const float*)d_in[17];
    const float* tsw2 = (const float*)d_in[18];
    const float* tsb2 = (const float*)d_in[19];
    const float* vsW1 = (const float*)d_in[20];
    const float* vsb1 = (const float*)d_in[21];
    const float* vsw2 = (const float*)d_in[22];
    const float* vsb2 = (const float*)d_in[23];
    const float* vtW1 = (const float*)d_in[24];
    const float* vtb1 = (const float*)d_in[25];
    const float* vtw2 = (const float*)d_in[26];
    const float* vtb2 = (const float*)d_in[27];
    float* out = (float*)d_out;

    // workspace layout (bytes):
    //   XG  bf16 [2048][32][384]  : 0           .. 50,331,648   (dead after 2nd k_scan2)
    //     -- video-path buffers overlay the XG region after the scans: --
    //     Xb bf16 [4096][1024]    : 0           ..  8,388,608
    //     Wb bf16 [768][1024]     : 8,388,608   ..  9,961,472
    //     G  f32  [4096][768]     : 9,961,472   .. 22,544,384
    //   embb bf16 [30522*128]     : 50,331,648  .. 58,145,280   (text path only;
    //     WibF bf16 [384*128]     : 58,145,280  .. 58,243,584    dead before E/V/C
    //     WibB bf16 [384*128]     : 58,243,584  .. 58,341,888    are written)
    //   E   f32  [2048][256]      : 50,331,648  ..  +2,097,152
    //   V   f32  [4096][256]      : 52,428,800  ..  +4,194,304
    //   C   f32  [16][128][256]   : 56,623,104  ..  +2,097,152
    //   Km  f32  [16][128][256]   : 58,720,256  ..  +2,097,152   (total 60,817,408)
    char* ws = (char*)d_ws;
    u16*   XG = (u16*)ws;
    u16*   Xb = (u16*)ws;
    u16*   Wb = (u16*)(ws + 8388608);
    float* G  = (float*)(ws + 9961472);
    u16*   embb = (u16*)(ws + 50331648);
    u16*   WibF = embb + 3906816;
    u16*   WibB = embb + 3955968;
    float* E  = (float*)(ws + 50331648);
    float* V  = (float*)(ws + 52428800);
    float* C  = (float*)(ws + 56623104);
    float* Km = (float*)(ws + 58720256);

    float* tf   = out + 2048;      // text_features (16,128,256)
    float* vseg = out + 526336;    // video_seg_probs (16,256)
    float* tsp  = out + 530432;    // text_summ_probs (16,128)
    float* vsp  = out + 532480;    // video_summ_probs (16,256)
    float* loss = out + 536576;    // ot_loss scalar
    float* T    = out + 536577;    // T (16,128,256)

    k_zero<<<8, 256, 0, stream>>>(out);

    // text path: bf16 emb/Wi convert, then MFMA xg GEMM + MFMA scan per direction
    k_cvte<<<3912, 256, 0, stream>>>(emb, WiF, WiB, embb);
    k_xg2<<<dim3(512, 3), 256, 0, stream>>>(ids, embb, WibF, biF, XG);
    k_scan2<<<256, 256, 0, stream>>>(XG, WhF, bhF, tf, 0);
    k_xg2<<<dim3(512, 3), 256, 0, stream>>>(ids, embb, WibB, biB, XG);
    k_scan2<<<256, 256, 0, stream>>>(XG, WhB, bhB, tf, 1);

    // video path (after scans: overlays XG region): one MFMA GEMM for both scorers + projection
    k_cvt<<<4864, 256, 0, stream>>>(vf, vsW1, vtW1, vpW, Xb, Wb);
    k_gemmv<<<dim3(32, 6), 256, 0, stream>>>(Xb, Wb, G);
    k_vepi<<<1024, 256, 0, stream>>>(G, vsb1, vsw2, vsb2, vtb1, vtw2, vtb2, vpb, V, vsp, vseg);

    k_tsum<<<2048, 128, 0, stream>>>(tf, tsW1, tsb1, tsw2, tsb2, tsp);
    k_eproj<<<256, 256, 0, stream>>>(tf, tsp, tpW, tpb, E);
    k_norm<<<1536, 256, 0, stream>>>(E, V);
    k_cost<<<dim3(16, 8), 256, 0, stream>>>(E, V, C, Km);
    k_sink<<<16, 512, 0, stream>>>(C, Km, T, loss);
}

// Round 9
// 510.211 us; speedup vs baseline: 2.3240x; 1.1225x over previous
//
#include <hip/hip_runtime.h>
#include <hip/hip_bf16.h>

typedef unsigned short u16;
typedef __attribute__((ext_vector_type(8))) short short8;
typedef __attribute__((ext_vector_type(4))) float f32x4;

static __device__ __forceinline__ float bf2f(u16 x) {
    unsigned int u = ((unsigned int)x) << 16;
    return __uint_as_float(u);
}
static __device__ __forceinline__ u16 f2bf(float f) {
    unsigned int u = __float_as_uint(f);
    unsigned int r = (u + 0x7fffu + ((u >> 16) & 1u)) >> 16;
    return (u16)r;
}
static __device__ __forceinline__ float sigmoidf(float x) {
    return 1.0f / (1.0f + expf(-x));
}
// fast transcendentals: v_exp_f32-based, rel err ~1e-6 (outputs go through
// sigmoid/bf16 anyway; thresholds are ~1.8e-2)
static __device__ __forceinline__ float fsig(float x) {
    return __fdividef(1.0f, 1.0f + __expf(-x));
}
static __device__ __forceinline__ float ftanh(float x) {
    return 1.0f - __fdividef(2.0f, 1.0f + __expf(2.0f * x));  // saturates to +-1 correctly
}

// ---------------- K0: zero text_seg_probs + loss slot ----------------
__global__ void k_zero(float* __restrict__ out) {
    int t = blockIdx.x * 256 + threadIdx.x;
    if (t < 2048) out[t] = 0.0f;
    if (t == 0) out[536576] = 0.0f;
}

// ---------------- K1a: convert emb table + WiF + WiB to bf16 ----------------
__global__ void k_cvte(const float* __restrict__ emb, const float* __restrict__ WiF,
                       const float* __restrict__ WiB, u16* __restrict__ dst) {
    long i4 = ((long)blockIdx.x * 256 + threadIdx.x) * 4;
    if (i4 >= 4005120) return;
    float4 v;
    if (i4 < 3906816) v = *(const float4*)(emb + i4);
    else if (i4 < 3955968) v = *(const float4*)(WiF + (i4 - 3906816));
    else v = *(const float4*)(WiB + (i4 - 3955968));
    ushort4 o;
    o.x = f2bf(v.x); o.y = f2bf(v.y); o.z = f2bf(v.z); o.w = f2bf(v.w);
    *(ushort4*)(dst + i4) = o;
}

// ---------------- K1b: xgt[token][seq][384] = gather(embb) @ Wib^T + bi (bf16 MFMA) ----------------
// Clone of validated k_gemmv; epilogue stores to the scan-friendly [t][seq][g*128+c] layout.
__global__ __launch_bounds__(256) void k_xg2(const int* __restrict__ ids, const u16* __restrict__ embb,
                                             const u16* __restrict__ Wib, const float* __restrict__ bi,
                                             u16* __restrict__ xgt) {
    __shared__ u16 As[128][40];
    __shared__ u16 Bs[128][40];
    const int t = threadIdx.x;
    const int m0 = blockIdx.x * 128, n0 = blockIdx.y * 128;
    const int w = t >> 6, l = t & 63;
    const int wr = w >> 1, wc = w & 1;
    const int lrow = l & 15, lk = (l >> 4) * 8;
    f32x4 acc[4][4] = {};
#pragma unroll
    for (int kk = 0; kk < 4; kk++) {
        const int k0 = kk * 32;
        int4 ra[2], rb[2];
#pragma unroll
        for (int it = 0; it < 2; it++) {
            int e = it * 256 + t;
            int row = e >> 2, c8 = (e & 3) * 8;
            int id = ids[m0 + row];
            ra[it] = *(const int4*)(embb + (long)id * 128 + k0 + c8);
            rb[it] = *(const int4*)(Wib + (long)(n0 + row) * 128 + k0 + c8);
        }
        __syncthreads();
#pragma unroll
        for (int it = 0; it < 2; it++) {
            int e = it * 256 + t;
            int row = e >> 2, c8 = (e & 3) * 8;
            *(int4*)&As[row][c8] = ra[it];
            *(int4*)&Bs[row][c8] = rb[it];
        }
        __syncthreads();
        short8 af[4], bf[4];
#pragma unroll
        for (int f = 0; f < 4; f++) {
            af[f] = *(const short8*)&As[wr * 64 + f * 16 + lrow][lk];
            bf[f] = *(const short8*)&Bs[wc * 64 + f * 16 + lrow][lk];
        }
#pragma unroll
        for (int fm = 0; fm < 4; fm++)
#pragma unroll
            for (int fn = 0; fn < 4; fn++)
                acc[fm][fn] = __builtin_amdgcn_mfma_f32_16x16x32_bf16(af[fm], bf[fn], acc[fm][fn], 0, 0, 0);
    }
    const int orow = (l >> 4) * 4, ocol = l & 15;
#pragma unroll
    for (int fm = 0; fm < 4; fm++)
#pragma unroll
        for (int fn = 0; fn < 4; fn++) {
            const int col = n0 + wc * 64 + fn * 16 + ocol;
            const float bbv = bi[col];
            const int row0 = m0 + wr * 64 + fm * 16 + orow;
#pragma unroll
            for (int r = 0; r < 4; r++) {
                const int mrow = row0 + r;   // seq*32 + token
                xgt[((long)(mrow & 31) * 2048 + (mrow >> 5)) * 384 + col]
                    = f2bf(acc[fm][fn][r] + bbv);
            }
        }
}

// ---------------- K2: MFMA GRU scan, 8 waves, double-buffered xg staging ----------------
// grid 256 (8 seqs/block, padded to M=16), block 512.
// Wave w owns hidden cols [w*16, w*16+16) for all 3 gates = 12 MFMA/step.
// xg staged cooperatively into LDS (coalesced [t][seq][384] rows), loads for
// step t+1 issued before step t's MFMA, written to LDS after the gate update.
__global__ __launch_bounds__(512) void k_scan3(const u16* __restrict__ xgt,
                                               const float* __restrict__ Wh,
                                               const float* __restrict__ bh,
                                               float* __restrict__ tf_out, int dir) {
    __shared__ u16 hbuf[2][16][140];   // pad 128->140: row bank base 6*lr mod 32, all distinct
    __shared__ u16 xbuf[2][8][392];    // pad 384->392
    const int t = threadIdx.x;
    const int w = t >> 6, l = t & 63;
    const int lr = l & 15, hi = l >> 4;
    const int seq0 = blockIdx.x * 8;

    short8 breg[3][4];
    float bb[3];
#pragma unroll
    for (int g = 0; g < 3; g++) {
        const int ncol = g * 128 + w * 16 + lr;
        const float* wrow = Wh + (long)ncol * 128;
        bb[g] = bh[ncol];
#pragma unroll
        for (int q = 0; q < 4; q++) {
            float4 a = *(const float4*)(wrow + q * 32 + hi * 8);
            float4 b = *(const float4*)(wrow + q * 32 + hi * 8 + 4);
            short8 s;
            s[0] = f2bf(a.x); s[1] = f2bf(a.y); s[2] = f2bf(a.z); s[3] = f2bf(a.w);
            s[4] = f2bf(b.x); s[5] = f2bf(b.y); s[6] = f2bf(b.z); s[7] = f2bf(b.w);
            breg[g][q] = s;
        }
    }
    for (int i = t; i < 2240; i += 512) ((int*)hbuf)[i] = 0;  // both h buffers
    const int seqr = t / 48, part = t % 48;                   // staging role (t<384)
    if (t < 384) {
        const int tp0 = dir ? 31 : 0;
        *(int4*)&xbuf[0][seqr][part * 8] =
            *(const int4*)(xgt + ((long)tp0 * 2048 + seq0 + seqr) * 384 + part * 8);
    }
    float hreg[4] = {0.f, 0.f, 0.f, 0.f};
    float macc[4] = {0.f, 0.f, 0.f, 0.f};
    __syncthreads();

    for (int tt = 0; tt < 32; tt++) {
        const int cur = tt & 1;
        // issue next-step xg loads early (HBM latency hides under MFMA+VALU)
        int4 pre;
        const bool do_pre = (tt < 31) && (t < 384);
        if (do_pre) {
            const int tpn = dir ? (30 - tt) : (tt + 1);
            pre = *(const int4*)(xgt + ((long)tpn * 2048 + seq0 + seqr) * 384 + part * 8);
        }
        short8 af[4];
#pragma unroll
        for (int q = 0; q < 4; q++)
            af[q] = *(const short8*)&hbuf[cur][lr][q * 32 + hi * 8];
        f32x4 acc[3];
#pragma unroll
        for (int g = 0; g < 3; g++) {
            f32x4 a = {0.f, 0.f, 0.f, 0.f};
#pragma unroll
            for (int q = 0; q < 4; q++)
                a = __builtin_amdgcn_mfma_f32_16x16x32_bf16(af[q], breg[g][q], a, 0, 0, 0);
            acc[g] = a;
        }
        if (hi < 2) {
            const int c = w * 16 + lr;
#pragma unroll
            for (int r = 0; r < 4; r++) {
                const int m = hi * 4 + r;
                float xr = bf2f(xbuf[cur][m][c]);
                float xz = bf2f(xbuf[cur][m][128 + c]);
                float xn = bf2f(xbuf[cur][m][256 + c]);
                float rg = fsig(xr + acc[0][r] + bb[0]);
                float zg = fsig(xz + acc[1][r] + bb[1]);
                float ng = ftanh(xn + rg * (acc[2][r] + bb[2]));
                float h = (1.0f - zg) * ng + zg * hreg[r];
                hreg[r] = h;
                macc[r] += h;
                hbuf[cur ^ 1][m][c] = f2bf(h);
            }
        }
        if (do_pre) *(int4*)&xbuf[cur ^ 1][seqr][part * 8] = pre;
        __syncthreads();
    }

    if (hi < 2) {
#pragma unroll
        for (int r = 0; r < 4; r++)
            tf_out[(long)(seq0 + hi * 4 + r) * 256 + dir * 128 + w * 16 + lr]
                = macc[r] * (1.0f / 32.0f);
    }
}

// ---------------- K3: text summary scorer (tanh MLP + sigmoid) ----------------
// grid 2048 (one row), block 128
__global__ void k_tsum(const float* __restrict__ tf, const float* __restrict__ W1,
                       const float* __restrict__ b1, const float* __restrict__ w2,
                       const float* __restrict__ b2, float* __restrict__ out) {
    __shared__ float x[256];
    __shared__ float wsum[2];
    const int row = blockIdx.x, t = threadIdx.x;
    x[t] = tf[(long)row * 256 + t];
    x[t + 128] = tf[(long)row * 256 + 128 + t];
    __syncthreads();
    float acc = 0.f;
    const float* w = W1 + (long)t * 256;
#pragma unroll 8
    for (int i = 0; i < 256; i += 4) {
        float4 w4 = *(const float4*)(w + i);
        acc += w4.x * x[i] + w4.y * x[i + 1] + w4.z * x[i + 2] + w4.w * x[i + 3];
    }
    float h = ftanh(acc + b1[t]) * w2[t];
    for (int o = 32; o > 0; o >>= 1) h += __shfl_xor(h, o);
    if ((t & 63) == 0) wsum[t >> 6] = h;
    __syncthreads();
    if (t == 0) out[row] = fsig(wsum[0] + wsum[1] + b2[0]);
}

// ---------------- K4a: convert vf and the three 256x1024 video weight mats to bf16 ----------------
__global__ void k_cvt(const float* __restrict__ vf, const float* __restrict__ wa,
                      const float* __restrict__ wb2, const float* __restrict__ wc2,
                      u16* __restrict__ Xb, u16* __restrict__ Wb) {
    long gid = (long)blockIdx.x * 256 + threadIdx.x;
    long i4 = gid * 4;
    float4 v;
    u16* dst;
    if (i4 < 4194304) {
        v = *(const float4*)(vf + i4);
        dst = Xb + i4;
    } else {
        long j = i4 - 4194304;
        dst = Wb + j;
        if (j < 262144) v = *(const float4*)(wa + j);
        else if (j < 524288) v = *(const float4*)(wb2 + (j - 262144));
        else v = *(const float4*)(wc2 + (j - 524288));
    }
    ushort4 o;
    o.x = f2bf(v.x); o.y = f2bf(v.y); o.z = f2bf(v.z); o.w = f2bf(v.w);
    *(ushort4*)dst = o;
}

// ---------------- K4b: G[4096][768] = Xb @ Wb^T (bf16 MFMA) ----------------
__global__ __launch_bounds__(256) void k_gemmv(const u16* __restrict__ Xb, const u16* __restrict__ Wb,
                                               float* __restrict__ G) {
    __shared__ u16 As[128][40];
    __shared__ u16 Bs[128][40];
    const int t = threadIdx.x;
    const int m0 = blockIdx.x * 128, n0 = blockIdx.y * 128;
    const int w = t >> 6, l = t & 63;
    const int wr = w >> 1, wc = w & 1;
    const int lrow = l & 15, lk = (l >> 4) * 8;
    f32x4 acc[4][4] = {};
    for (int kk = 0; kk < 32; kk++) {
        const int k0 = kk * 32;
        int4 ra[2], rb[2];
#pragma unroll
        for (int it = 0; it < 2; it++) {
            int e = it * 256 + t;
            int row = e >> 2, c8 = (e & 3) * 8;
            ra[it] = *(const int4*)(Xb + (long)(m0 + row) * 1024 + k0 + c8);
            rb[it] = *(const int4*)(Wb + (long)(n0 + row) * 1024 + k0 + c8);
        }
        __syncthreads();
#pragma unroll
        for (int it = 0; it < 2; it++) {
            int e = it * 256 + t;
            int row = e >> 2, c8 = (e & 3) * 8;
            *(int4*)&As[row][c8] = ra[it];
            *(int4*)&Bs[row][c8] = rb[it];
        }
        __syncthreads();
        short8 af[4], bf[4];
#pragma unroll
        for (int f = 0; f < 4; f++) {
            af[f] = *(const short8*)&As[wr * 64 + f * 16 + lrow][lk];
            bf[f] = *(const short8*)&Bs[wc * 64 + f * 16 + lrow][lk];
        }
#pragma unroll
        for (int fm = 0; fm < 4; fm++)
#pragma unroll
            for (int fn = 0; fn < 4; fn++)
                acc[fm][fn] = __builtin_amdgcn_mfma_f32_16x16x32_bf16(af[fm], bf[fn], acc[fm][fn], 0, 0, 0);
    }
    const int orow = (l >> 4) * 4, ocol = l & 15;
#pragma unroll
    for (int fm = 0; fm < 4; fm++)
#pragma unroll
        for (int fn = 0; fn < 4; fn++) {
            long base = (long)(m0 + wr * 64 + fm * 16 + orow) * 768 + n0 + wc * 64 + fn * 16 + ocol;
#pragma unroll
            for (int r = 0; r < 4; r++)
                G[base + (long)r * 768] = acc[fm][fn][r];
        }
}

// ---------------- K4c: video epilogue — scorer layer-2 + scaled V projection ----------------
__global__ void k_vepi(const float* __restrict__ G,
                       const float* __restrict__ bv, const float* __restrict__ w2v, const float* __restrict__ b2v,
                       const float* __restrict__ bt, const float* __restrict__ w2t, const float* __restrict__ b2t,
                       const float* __restrict__ vpb,
                       float* __restrict__ V, float* __restrict__ vsp, float* __restrict__ vseg) {
    const int r = blockIdx.x * 4 + (threadIdx.x >> 6);
    const int lane = threadIdx.x & 63;
    const float* g = G + (long)r * 768;
    float s1 = 0.f, s2 = 0.f;
#pragma unroll
    for (int c = 0; c < 4; c++) {
        int h = lane + c * 64;
        s1 += ftanh(g[h] + bv[h]) * w2v[h];
        s2 += fmaxf(g[256 + h] + bt[h], 0.0f) * w2t[h];
    }
    for (int o = 32; o > 0; o >>= 1) { s1 += __shfl_xor(s1, o); s2 += __shfl_xor(s2, o); }
    float p = fsig(s1 + b2v[0]);
    if (lane == 0) {
        vsp[r] = p;
        vseg[r] = fsig(s2 + b2t[0]);
    }
#pragma unroll
    for (int c = 0; c < 4; c++) {
        int a = lane + c * 64;
        V[(long)r * 256 + a] = vpb[a] + p * g[512 + a];
    }
}

// ---------------- K5a: E_proj = (tf * tsp) @ tproj_W^T + b ----------------
__global__ void k_eproj(const float* __restrict__ tf, const float* __restrict__ tsp,
                        const float* __restrict__ W, const float* __restrict__ b,
                        float* __restrict__ E) {
    __shared__ float x[8][256];
    __shared__ float p[8];
    const int r0 = blockIdx.x * 8, t = threadIdx.x;
    const float4* src = (const float4*)(tf + (long)r0 * 256);
    for (int i = t; i < 512; i += 256) ((float4*)&x[0][0])[i] = src[i];
    if (t < 8) p[t] = tsp[r0 + t];
    __syncthreads();
    float acc[8] = {};
    const float* w = W + (long)t * 256;
    for (int i = 0; i < 256; i += 4) {
        float4 w4 = *(const float4*)(w + i);
#pragma unroll
        for (int r = 0; r < 8; r++) {
            float4 x4 = *(const float4*)&x[r][i];
            acc[r] += w4.x * x4.x + w4.y * x4.y + w4.z * x4.z + w4.w * x4.w;
        }
    }
    const float bb = b[t];
#pragma unroll
    for (int r = 0; r < 8; r++) E[(long)(r0 + r) * 256 + t] = bb + p[r] * acc[r];
}

// ---------------- K6: row L2-normalize E (2048 rows) and V (4096 rows) in place ----------------
__global__ void k_norm(float* __restrict__ E, float* __restrict__ V) {
    const int w = threadIdx.x >> 6, lane = threadIdx.x & 63;
    const int row = blockIdx.x * 4 + w;
    float* ptr = (row < 2048) ? (E + (long)row * 256) : (V + (long)(row - 2048) * 256);
    float4 v = ((float4*)ptr)[lane];
    float s = v.x * v.x + v.y * v.y + v.z * v.z + v.w * v.w;
    for (int o = 32; o > 0; o >>= 1) s += __shfl_xor(s, o);
    float sc = 1.0f / (sqrtf(s) + 1e-12f);
    v.x *= sc; v.y *= sc; v.z *= sc; v.w *= sc;
    ((float4*)ptr)[lane] = v;
}

// ---------------- K7: C = 1 - En . Vn^T  and Km = exp(-C/reg) ----------------
__global__ void k_cost(const float* __restrict__ E, const float* __restrict__ V,
                       float* __restrict__ C, float* __restrict__ Km) {
    __shared__ float en[16][256];
    const int b = blockIdx.x, k0 = blockIdx.y * 16, t = threadIdx.x;
    const float4* esrc = (const float4*)(E + ((long)b * 128 + k0) * 256);
    for (int i = t; i < 1024; i += 256) ((float4*)&en[0][0])[i] = esrc[i];
    __syncthreads();
    float acc[16] = {};
    const float* vrow = V + ((long)b * 256 + t) * 256;
    for (int i = 0; i < 256; i += 4) {
        float4 v4 = *(const float4*)(vrow + i);
#pragma unroll
        for (int k = 0; k < 16; k++) {
            float4 e4 = *(const float4*)&en[k][i];
            acc[k] += e4.x * v4.x + e4.y * v4.y + e4.z * v4.z + e4.w * v4.w;
        }
    }
#pragma unroll
    for (int k = 0; k < 16; k++) {
        float c = 1.0f - acc[k];
        long idx = (long)b * 32768 + (long)(k0 + k) * 256 + t;
        C[idx] = c;
        Km[idx] = __expf(-20.0f * c);
    }
}

// ---------------- K8: Sinkhorn iterations + T + loss (precise math kept) ----------------
__global__ void k_sink(const float* __restrict__ C, const float* __restrict__ Km,
                       float* __restrict__ T, float* __restrict__ loss) {
    __shared__ float u[128];
    __shared__ float v[256];
    __shared__ float red[8];
    const int b = blockIdx.x, t = threadIdx.x;
    const float* Kb = Km + (long)b * 32768;
    const float* Cb = C + (long)b * 32768;
    if (t < 128) u[t] = 1.0f / 128.0f;
    if (t < 256) v[t] = 1.0f / 256.0f;
    __syncthreads();
    for (int it = 0; it < 10; it++) {
        {
            const int k = t >> 2, q = t & 3;
            const float* kr = Kb + (long)k * 256 + q * 64;
            float s = 0.f;
#pragma unroll 4
            for (int m = 0; m < 64; m += 4) {
                float4 k4 = *(const float4*)(kr + m);
                float4 vv = *(const float4*)&v[q * 64 + m];
                s += k4.x * vv.x + k4.y * vv.y + k4.z * vv.z + k4.w * vv.w;
            }
            s += __shfl_xor(s, 1);
            s += __shfl_xor(s, 2);
            float un = (1.0f / 128.0f) / (s + 1e-8f);
            u[k] = un;
            __syncthreads();
        }
        {
            const int m = t >> 1, q = t & 1;
            float s = 0.f;
            for (int k = 0; k < 64; k += 4) {
                float4 u4 = *(const float4*)&u[q * 64 + k];
                s += Kb[(long)(q * 64 + k + 0) * 256 + m] * u4.x;
                s += Kb[(long)(q * 64 + k + 1) * 256 + m] * u4.y;
                s += Kb[(long)(q * 64 + k + 2) * 256 + m] * u4.z;
                s += Kb[(long)(q * 64 + k + 3) * 256 + m] * u4.w;
            }
            s += __shfl_xor(s, 1);
            float vn = (1.0f / 256.0f) / (s + 1e-8f);
            v[m] = vn;
            __syncthreads();
        }
    }
    float part = 0.f;
    for (int i = 0; i < 64; i++) {
        int idx = i * 512 + t;
        int k = idx >> 8, m = idx & 255;
        float tv = u[k] * Kb[idx] * v[m];
        T[(long)b * 32768 + idx] = tv;
        part += tv * Cb[idx];
    }
    for (int o = 32; o > 0; o >>= 1) part += __shfl_xor(part, o);
    if ((t & 63) == 0) red[t >> 6] = part;
    __syncthreads();
    if (t == 0) {
        float s = red[0] + red[1] + red[2] + red[3] + red[4] + red[5] + red[6] + red[7];
        atomicAdd(loss, s * (1.0f / 16.0f));
    }
}

extern "C" void kernel_launch(void* const* d_in, const int* in_sizes, int n_in,
                              void* d_out, int out_size, void* d_ws, size_t ws_size,
                              hipStream_t stream) {
    const int*   ids  = (const int*)d_in[0];
    const float* vf   = (const float*)d_in[2];
    const float* emb  = (const float*)d_in[3];
    const float* WiF  = (const float*)d_in[4];
    const float* WhF  = (const float*)d_in[5];
    const float* biF  = (const float*)d_in[6];
    const float* bhF  = (const float*)d_in[7];
    const float* WiB  = (const float*)d_in[8];
    const float* WhB  = (const float*)d_in[9];
    const float* biB  = (const float*)d_in[10];
    const float* bhB  = (const float*)d_in[11];
    const float* tpW  = (const float*)d_in[12];
    const float* tpb  = (const float*)d_in[13];
    const float* vpW  = (const float*)d_in[14];
    const float* vpb  = (const float*)d_in[15];
    const float* tsW1 = (const float*)d_in[16];
    const float* tsb1 = (const float*)d_in[17];
    const float* tsw2 = (const float*)d_in[18];
    const float* tsb2 = (const float*)d_in[19];
    const float* vsW1 = (const float*)d_in[20];
    const float* vsb1 = (const float*)d_in[21];
    const float* vsw2 = (const float*)d_in[22];
    const float* vsb2 = (const float*)d_in[23];
    const float* vtW1 = (const float*)d_in[24];
    const float* vtb1 = (const float*)d_in[25];
    const float* vtw2 = (const float*)d_in[26];
    const float* vtb2 = (const float*)d_in[27];
    float* out = (float*)d_out;

    // workspace layout (bytes): identical footprint to R8 (60,817,408 total)
    //   XGT bf16 [32][2048][384]  : 0           .. 50,331,648   (dead after 2nd k_scan3)
    //     Xb bf16 [4096][1024]    : 0           ..  8,388,608   (video overlay)
    //     Wb bf16 [768][1024]     : 8,388,608   ..  9,961,472
    //     G  f32  [4096][768]     : 9,961,472   .. 22,544,384
    //   embb bf16 + WibF + WibB   : 50,331,648  .. 58,341,888   (dead before E/V/C)
    //   E   f32  [2048][256]      : 50,331,648
    //   V   f32  [4096][256]      : 52,428,800
    //   C   f32  [16][128][256]   : 56,623,104
    //   Km  f32  [16][128][256]   : 58,720,256
    char* ws = (char*)d_ws;
    u16*   XGT = (u16*)ws;
    u16*   Xb = (u16*)ws;
    u16*   Wb = (u16*)(ws + 8388608);
    float* G  = (float*)(ws + 9961472);
    u16*   embb = (u16*)(ws + 50331648);
    u16*   WibF = embb + 3906816;
    u16*   WibB = embb + 3955968;
    float* E  = (float*)(ws + 50331648);
    float* V  = (float*)(ws + 52428800);
    float* C  = (float*)(ws + 56623104);
    float* Km = (float*)(ws + 58720256);

    float* tf   = out + 2048;
    float* vseg = out + 526336;
    float* tsp  = out + 530432;
    float* vsp  = out + 532480;
    float* loss = out + 536576;
    float* T    = out + 536577;

    k_zero<<<8, 256, 0, stream>>>(out);

    // text path
    k_cvte<<<3912, 256, 0, stream>>>(emb, WiF, WiB, embb);
    k_xg2<<<dim3(512, 3), 256, 0, stream>>>(ids, embb, WibF, biF, XGT);
    k_scan3<<<256, 512, 0, stream>>>(XGT, WhF, bhF, tf, 0);
    k_xg2<<<dim3(512, 3), 256, 0, stream>>>(ids, embb, WibB, biB, XGT);
    k_scan3<<<256, 512, 0, stream>>>(XGT, WhB, bhB, tf, 1);

    // video path (overlays XGT region after scans)
    k_cvt<<<4864, 256, 0, stream>>>(vf, vsW1, vtW1, vpW, Xb, Wb);
    k_gemmv<<<dim3(32, 6), 256, 0, stream>>>(Xb, Wb, G);
    k_vepi<<<1024, 256, 0, stream>>>(G, vsb1, vsw2, vsb2, vtb1, vtw2, vtb2, vpb, V, vsp, vseg);

    k_tsum<<<2048, 128, 0, stream>>>(tf, tsW1, tsb1, tsw2, tsb2, tsp);
    k_eproj<<<256, 256, 0, stream>>>(tf, tsp, tpW, tpb, E);
    k_norm<<<1536, 256, 0, stream>>>(E, V);
    k_cost<<<dim3(16, 8), 256, 0, stream>>>(E, V, C, Km);
    k_sink<<<16, 512, 0, stream>>>(C, Km, T, loss);
}

// Round 10
// 495.648 us; speedup vs baseline: 2.3923x; 1.0294x over previous
//
#include <hip/hip_runtime.h>
#include <hip/hip_bf16.h>

typedef unsigned short u16;
typedef __attribute__((ext_vector_type(8))) short short8;
typedef __attribute__((ext_vector_type(4))) float f32x4;

static __device__ __forceinline__ float bf2f(u16 x) {
    unsigned int u = ((unsigned int)x) << 16;
    return __uint_as_float(u);
}
static __device__ __forceinline__ u16 f2bf(float f) {
    unsigned int u = __float_as_uint(f);
    unsigned int r = (u + 0x7fffu + ((u >> 16) & 1u)) >> 16;
    return (u16)r;
}
// fast transcendentals: v_exp_f32-based, rel err ~1e-6
static __device__ __forceinline__ float fsig(float x) {
    return __fdividef(1.0f, 1.0f + __expf(-x));
}
static __device__ __forceinline__ float ftanh(float x) {
    return 1.0f - __fdividef(2.0f, 1.0f + __expf(2.0f * x));
}

// ---------------- K0: zero text_seg_probs + loss slot ----------------
__global__ void k_zero(float* __restrict__ out) {
    int t = blockIdx.x * 256 + threadIdx.x;
    if (t < 2048) out[t] = 0.0f;
    if (t == 0) out[536576] = 0.0f;
}

// ---------------- K1a: convert emb table + WiF + WiB to bf16 ----------------
__global__ void k_cvte(const float* __restrict__ emb, const float* __restrict__ WiF,
                       const float* __restrict__ WiB, u16* __restrict__ dst) {
    long i4 = ((long)blockIdx.x * 256 + threadIdx.x) * 4;
    if (i4 >= 4005120) return;
    float4 v;
    if (i4 < 3906816) v = *(const float4*)(emb + i4);
    else if (i4 < 3955968) v = *(const float4*)(WiF + (i4 - 3906816));
    else v = *(const float4*)(WiB + (i4 - 3955968));
    ushort4 o;
    o.x = f2bf(v.x); o.y = f2bf(v.y); o.z = f2bf(v.z); o.w = f2bf(v.w);
    *(ushort4*)(dst + i4) = o;
}

// ---------------- K1b: xgt[token][seq][384] = gather(embb) @ Wib^T + bi (bf16 MFMA) ----------------
__global__ __launch_bounds__(256) void k_xg2(const int* __restrict__ ids, const u16* __restrict__ embb,
                                             const u16* __restrict__ Wib, const float* __restrict__ bi,
                                             u16* __restrict__ xgt) {
    __shared__ u16 As[128][40];
    __shared__ u16 Bs[128][40];
    const int t = threadIdx.x;
    const int m0 = blockIdx.x * 128, n0 = blockIdx.y * 128;
    const int w = t >> 6, l = t & 63;
    const int wr = w >> 1, wc = w & 1;
    const int lrow = l & 15, lk = (l >> 4) * 8;
    f32x4 acc[4][4] = {};
#pragma unroll
    for (int kk = 0; kk < 4; kk++) {
        const int k0 = kk * 32;
        int4 ra[2], rb[2];
#pragma unroll
        for (int it = 0; it < 2; it++) {
            int e = it * 256 + t;
            int row = e >> 2, c8 = (e & 3) * 8;
            int id = ids[m0 + row];
            ra[it] = *(const int4*)(embb + (long)id * 128 + k0 + c8);
            rb[it] = *(const int4*)(Wib + (long)(n0 + row) * 128 + k0 + c8);
        }
        __syncthreads();
#pragma unroll
        for (int it = 0; it < 2; it++) {
            int e = it * 256 + t;
            int row = e >> 2, c8 = (e & 3) * 8;
            *(int4*)&As[row][c8] = ra[it];
            *(int4*)&Bs[row][c8] = rb[it];
        }
        __syncthreads();
        short8 af[4], bf[4];
#pragma unroll
        for (int f = 0; f < 4; f++) {
            af[f] = *(const short8*)&As[wr * 64 + f * 16 + lrow][lk];
            bf[f] = *(const short8*)&Bs[wc * 64 + f * 16 + lrow][lk];
        }
#pragma unroll
        for (int fm = 0; fm < 4; fm++)
#pragma unroll
            for (int fn = 0; fn < 4; fn++)
                acc[fm][fn] = __builtin_amdgcn_mfma_f32_16x16x32_bf16(af[fm], bf[fn], acc[fm][fn], 0, 0, 0);
    }
    const int orow = (l >> 4) * 4, ocol = l & 15;
#pragma unroll
    for (int fm = 0; fm < 4; fm++)
#pragma unroll
        for (int fn = 0; fn < 4; fn++) {
            const int col = n0 + wc * 64 + fn * 16 + ocol;
            const float bbv = bi[col];
            const int row0 = m0 + wr * 64 + fm * 16 + orow;
#pragma unroll
            for (int r = 0; r < 4; r++) {
                const int mrow = row0 + r;   // seq*32 + token
                xgt[((long)(mrow & 31) * 2048 + (mrow >> 5)) * 384 + col]
                    = f2bf(acc[fm][fn][r] + bbv);
            }
        }
}

// ---------------- K2: MFMA GRU scan, 8 waves, double-buffered xg staging ----------------
__global__ __launch_bounds__(512) void k_scan3(const u16* __restrict__ xgt,
                                               const float* __restrict__ Wh,
                                               const float* __restrict__ bh,
                                               float* __restrict__ tf_out, int dir) {
    __shared__ u16 hbuf[2][16][140];
    __shared__ u16 xbuf[2][8][392];
    const int t = threadIdx.x;
    const int w = t >> 6, l = t & 63;
    const int lr = l & 15, hi = l >> 4;
    const int seq0 = blockIdx.x * 8;

    short8 breg[3][4];
    float bb[3];
#pragma unroll
    for (int g = 0; g < 3; g++) {
        const int ncol = g * 128 + w * 16 + lr;
        const float* wrow = Wh + (long)ncol * 128;
        bb[g] = bh[ncol];
#pragma unroll
        for (int q = 0; q < 4; q++) {
            float4 a = *(const float4*)(wrow + q * 32 + hi * 8);
            float4 b = *(const float4*)(wrow + q * 32 + hi * 8 + 4);
            short8 s;
            s[0] = f2bf(a.x); s[1] = f2bf(a.y); s[2] = f2bf(a.z); s[3] = f2bf(a.w);
            s[4] = f2bf(b.x); s[5] = f2bf(b.y); s[6] = f2bf(b.z); s[7] = f2bf(b.w);
            breg[g][q] = s;
        }
    }
    for (int i = t; i < 2240; i += 512) ((int*)hbuf)[i] = 0;
    const int seqr = t / 48, part = t % 48;
    if (t < 384) {
        const int tp0 = dir ? 31 : 0;
        *(int4*)&xbuf[0][seqr][part * 8] =
            *(const int4*)(xgt + ((long)tp0 * 2048 + seq0 + seqr) * 384 + part * 8);
    }
    float hreg[4] = {0.f, 0.f, 0.f, 0.f};
    float macc[4] = {0.f, 0.f, 0.f, 0.f};
    __syncthreads();

    for (int tt = 0; tt < 32; tt++) {
        const int cur = tt & 1;
        int4 pre;
        const bool do_pre = (tt < 31) && (t < 384);
        if (do_pre) {
            const int tpn = dir ? (30 - tt) : (tt + 1);
            pre = *(const int4*)(xgt + ((long)tpn * 2048 + seq0 + seqr) * 384 + part * 8);
        }
        short8 af[4];
#pragma unroll
        for (int q = 0; q < 4; q++)
            af[q] = *(const short8*)&hbuf[cur][lr][q * 32 + hi * 8];
        f32x4 acc[3];
#pragma unroll
        for (int g = 0; g < 3; g++) {
            f32x4 a = {0.f, 0.f, 0.f, 0.f};
#pragma unroll
            for (int q = 0; q < 4; q++)
                a = __builtin_amdgcn_mfma_f32_16x16x32_bf16(af[q], breg[g][q], a, 0, 0, 0);
            acc[g] = a;
        }
        if (hi < 2) {
            const int c = w * 16 + lr;
#pragma unroll
            for (int r = 0; r < 4; r++) {
                const int m = hi * 4 + r;
                float xr = bf2f(xbuf[cur][m][c]);
                float xz = bf2f(xbuf[cur][m][128 + c]);
                float xn = bf2f(xbuf[cur][m][256 + c]);
                float rg = fsig(xr + acc[0][r] + bb[0]);
                float zg = fsig(xz + acc[1][r] + bb[1]);
                float ng = ftanh(xn + rg * (acc[2][r] + bb[2]));
                float h = (1.0f - zg) * ng + zg * hreg[r];
                hreg[r] = h;
                macc[r] += h;
                hbuf[cur ^ 1][m][c] = f2bf(h);
            }
        }
        if (do_pre) *(int4*)&xbuf[cur ^ 1][seqr][part * 8] = pre;
        __syncthreads();
    }

    if (hi < 2) {
#pragma unroll
        for (int r = 0; r < 4; r++)
            tf_out[(long)(seq0 + hi * 4 + r) * 256 + dir * 128 + w * 16 + lr]
                = macc[r] * (1.0f / 32.0f);
    }
}

// ---------------- K3: text summary scorer (tanh MLP + sigmoid) ----------------
__global__ void k_tsum(const float* __restrict__ tf, const float* __restrict__ W1,
                       const float* __restrict__ b1, const float* __restrict__ w2,
                       const float* __restrict__ b2, float* __restrict__ out) {
    __shared__ float x[256];
    __shared__ float wsum[2];
    const int row = blockIdx.x, t = threadIdx.x;
    x[t] = tf[(long)row * 256 + t];
    x[t + 128] = tf[(long)row * 256 + 128 + t];
    __syncthreads();
    float acc = 0.f;
    const float* w = W1 + (long)t * 256;
#pragma unroll 8
    for (int i = 0; i < 256; i += 4) {
        float4 w4 = *(const float4*)(w + i);
        acc += w4.x * x[i] + w4.y * x[i + 1] + w4.z * x[i + 2] + w4.w * x[i + 3];
    }
    float h = ftanh(acc + b1[t]) * w2[t];
    for (int o = 32; o > 0; o >>= 1) h += __shfl_xor(h, o);
    if ((t & 63) == 0) wsum[t >> 6] = h;
    __syncthreads();
    if (t == 0) out[row] = fsig(wsum[0] + wsum[1] + b2[0]);
}

// ---------------- K4a: convert vf and the three 256x1024 video weight mats to bf16 ----------------
__global__ void k_cvt(const float* __restrict__ vf, const float* __restrict__ wa,
                      const float* __restrict__ wb2, const float* __restrict__ wc2,
                      u16* __restrict__ Xb, u16* __restrict__ Wb) {
    long gid = (long)blockIdx.x * 256 + threadIdx.x;
    long i4 = gid * 4;
    float4 v;
    u16* dst;
    if (i4 < 4194304) {
        v = *(const float4*)(vf + i4);
        dst = Xb + i4;
    } else {
        long j = i4 - 4194304;
        dst = Wb + j;
        if (j < 262144) v = *(const float4*)(wa + j);
        else if (j < 524288) v = *(const float4*)(wb2 + (j - 262144));
        else v = *(const float4*)(wc2 + (j - 524288));
    }
    ushort4 o;
    o.x = f2bf(v.x); o.y = f2bf(v.y); o.z = f2bf(v.z); o.w = f2bf(v.w);
    *(ushort4*)dst = o;
}

// ---------------- K4b: G[4096][768] = Xb @ Wb^T (bf16 MFMA, pipelined) ----------------
// Quad-major LDS [4][130][8]: fragment reads are row-contiguous (16 lanes x 16B
// consecutive => conflict-free); quad bases at banks {0,8,16,24} => staging
// writes conflict-free. Register prefetch of tile kk+1 before MFMA of kk;
// single barrier per iteration (writes go to the other buffer).
__global__ __launch_bounds__(256) void k_gemmv(const u16* __restrict__ Xb, const u16* __restrict__ Wb,
                                               float* __restrict__ G) {
    __shared__ u16 As[2][4][130][8];
    __shared__ u16 Bs[2][4][130][8];
    const int t = threadIdx.x;
    const int m0 = blockIdx.x * 128, n0 = blockIdx.y * 128;
    const int w = t >> 6, l = t & 63;
    const int wr = w >> 1, wc = w & 1;
    const int lrow = l & 15, lq = l >> 4;
    const int ldr = t >> 2, ldq = t & 3;   // loader: rows ldr, ldr+64; k-quad ldq
    f32x4 acc[4][4] = {};
    int4 ra[2], rb[2];
#pragma unroll
    for (int it = 0; it < 2; it++) {
        int row = ldr + it * 64;
        ra[it] = *(const int4*)(Xb + (long)(m0 + row) * 1024 + ldq * 8);
        rb[it] = *(const int4*)(Wb + (long)(n0 + row) * 1024 + ldq * 8);
    }
#pragma unroll
    for (int it = 0; it < 2; it++) {
        int row = ldr + it * 64;
        *(int4*)&As[0][ldq][row][0] = ra[it];
        *(int4*)&Bs[0][ldq][row][0] = rb[it];
    }
    __syncthreads();
    for (int kk = 0; kk < 32; kk++) {
        const int cur = kk & 1;
        if (kk < 31) {
            const int k0 = (kk + 1) * 32;
#pragma unroll
            for (int it = 0; it < 2; it++) {
                int row = ldr + it * 64;
                ra[it] = *(const int4*)(Xb + (long)(m0 + row) * 1024 + k0 + ldq * 8);
                rb[it] = *(const int4*)(Wb + (long)(n0 + row) * 1024 + k0 + ldq * 8);
            }
        }
        short8 af[4], bf[4];
#pragma unroll
        for (int f = 0; f < 4; f++) {
            af[f] = *(const short8*)&As[cur][lq][wr * 64 + f * 16 + lrow][0];
            bf[f] = *(const short8*)&Bs[cur][lq][wc * 64 + f * 16 + lrow][0];
        }
#pragma unroll
        for (int fm = 0; fm < 4; fm++)
#pragma unroll
            for (int fn = 0; fn < 4; fn++)
                acc[fm][fn] = __builtin_amdgcn_mfma_f32_16x16x32_bf16(af[fm], bf[fn], acc[fm][fn], 0, 0, 0);
        if (kk < 31) {
#pragma unroll
            for (int it = 0; it < 2; it++) {
                int row = ldr + it * 64;
                *(int4*)&As[cur ^ 1][ldq][row][0] = ra[it];
                *(int4*)&Bs[cur ^ 1][ldq][row][0] = rb[it];
            }
        }
        __syncthreads();
    }
    const int orow = (l >> 4) * 4, ocol = l & 15;
#pragma unroll
    for (int fm = 0; fm < 4; fm++)
#pragma unroll
        for (int fn = 0; fn < 4; fn++) {
            long base = (long)(m0 + wr * 64 + fm * 16 + orow) * 768 + n0 + wc * 64 + fn * 16 + ocol;
#pragma unroll
            for (int r = 0; r < 4; r++)
                G[base + (long)r * 768] = acc[fm][fn][r];
        }
}

// ---------------- K4c: video epilogue — scorer layer-2 + scaled V projection ----------------
__global__ void k_vepi(const float* __restrict__ G,
                       const float* __restrict__ bv, const float* __restrict__ w2v, const float* __restrict__ b2v,
                       const float* __restrict__ bt, const float* __restrict__ w2t, const float* __restrict__ b2t,
                       const float* __restrict__ vpb,
                       float* __restrict__ V, float* __restrict__ vsp, float* __restrict__ vseg) {
    const int r = blockIdx.x * 4 + (threadIdx.x >> 6);
    const int lane = threadIdx.x & 63;
    const float* g = G + (long)r * 768;
    float s1 = 0.f, s2 = 0.f;
#pragma unroll
    for (int c = 0; c < 4; c++) {
        int h = lane + c * 64;
        s1 += ftanh(g[h] + bv[h]) * w2v[h];
        s2 += fmaxf(g[256 + h] + bt[h], 0.0f) * w2t[h];
    }
    for (int o = 32; o > 0; o >>= 1) { s1 += __shfl_xor(s1, o); s2 += __shfl_xor(s2, o); }
    float p = fsig(s1 + b2v[0]);
    if (lane == 0) {
        vsp[r] = p;
        vseg[r] = fsig(s2 + b2t[0]);
    }
#pragma unroll
    for (int c = 0; c < 4; c++) {
        int a = lane + c * 64;
        V[(long)r * 256 + a] = vpb[a] + p * g[512 + a];
    }
}

// ---------------- K5a: E_proj = (tf * tsp) @ tproj_W^T + b ----------------
__global__ void k_eproj(const float* __restrict__ tf, const float* __restrict__ tsp,
                        const float* __restrict__ W, const float* __restrict__ b,
                        float* __restrict__ E) {
    __shared__ float x[8][256];
    __shared__ float p[8];
    const int r0 = blockIdx.x * 8, t = threadIdx.x;
    const float4* src = (const float4*)(tf + (long)r0 * 256);
    for (int i = t; i < 512; i += 256) ((float4*)&x[0][0])[i] = src[i];
    if (t < 8) p[t] = tsp[r0 + t];
    __syncthreads();
    float acc[8] = {};
    const float* w = W + (long)t * 256;
    for (int i = 0; i < 256; i += 4) {
        float4 w4 = *(const float4*)(w + i);
#pragma unroll
        for (int r = 0; r < 8; r++) {
            float4 x4 = *(const float4*)&x[r][i];
            acc[r] += w4.x * x4.x + w4.y * x4.y + w4.z * x4.z + w4.w * x4.w;
        }
    }
    const float bb = b[t];
#pragma unroll
    for (int r = 0; r < 8; r++) E[(long)(r0 + r) * 256 + t] = bb + p[r] * acc[r];
}

// ---------------- K6: row L2-normalize E (2048 rows) and V (4096 rows) in place ----------------
__global__ void k_norm(float* __restrict__ E, float* __restrict__ V) {
    const int w = threadIdx.x >> 6, lane = threadIdx.x & 63;
    const int row = blockIdx.x * 4 + w;
    float* ptr = (row < 2048) ? (E + (long)row * 256) : (V + (long)(row - 2048) * 256);
    float4 v = ((float4*)ptr)[lane];
    float s = v.x * v.x + v.y * v.y + v.z * v.z + v.w * v.w;
    for (int o = 32; o > 0; o >>= 1) s += __shfl_xor(s, o);
    float sc = 1.0f / (sqrtf(s) + 1e-12f);
    v.x *= sc; v.y *= sc; v.z *= sc; v.w *= sc;
    ((float4*)ptr)[lane] = v;
}

// ---------------- K7: C = 1 - En . Vn^T  and Km = exp(-C/reg) ----------------
__global__ void k_cost(const float* __restrict__ E, const float* __restrict__ V,
                       float* __restrict__ C, float* __restrict__ Km) {
    __shared__ float en[16][256];
    const int b = blockIdx.x, k0 = blockIdx.y * 16, t = threadIdx.x;
    const float4* esrc = (const float4*)(E + ((long)b * 128 + k0) * 256);
    for (int i = t; i < 1024; i += 256) ((float4*)&en[0][0])[i] = esrc[i];
    __syncthreads();
    float acc[16] = {};
    const float* vrow = V + ((long)b * 256 + t) * 256;
    for (int i = 0; i < 256; i += 4) {
        float4 v4 = *(const float4*)(vrow + i);
#pragma unroll
        for (int k = 0; k < 16; k++) {
            float4 e4 = *(const float4*)&en[k][i];
            acc[k] += e4.x * v4.x + e4.y * v4.y + e4.z * v4.z + e4.w * v4.w;
        }
    }
#pragma unroll
    for (int k = 0; k < 16; k++) {
        float c = 1.0f - acc[k];
        long idx = (long)b * 32768 + (long)(k0 + k) * 256 + t;
        C[idx] = c;
        Km[idx] = __expf(-20.0f * c);
    }
}

// ---------------- K8a: Sinkhorn u/v iterations, Km cached in LDS ----------------
// grid 16 (one per batch), block 512. Km per batch = 128KB -> LDS once;
// 10 iterations run entirely from LDS. Outputs u[128],v[256] per batch.
__global__ __launch_bounds__(512) void k_sink2(const float* __restrict__ Km, float* __restrict__ UV) {
    __shared__ float Kl[128][256];
    __shared__ float u[128];
    __shared__ float v[256];
    const int b = blockIdx.x, t = threadIdx.x;
    const float* Kb = Km + (long)b * 32768;
    for (int i = t; i < 8192; i += 512)
        ((float4*)&Kl[0][0])[i] = ((const float4*)Kb)[i];
    if (t < 128) u[t] = 1.0f / 128.0f;
    if (t < 256) v[t] = 1.0f / 256.0f;
    __syncthreads();
    for (int it = 0; it < 10; it++) {
        {   // u = mu / (Km @ v + 1e-8); t = k*4+q, q covers 64 m's
            const int k = t >> 2, q = t & 3;
            const float* kr = &Kl[k][q * 64];
            float s = 0.f;
#pragma unroll 4
            for (int m = 0; m < 64; m += 4) {
                float4 k4 = *(const float4*)(kr + m);
                float4 vv = *(const float4*)&v[q * 64 + m];
                s += k4.x * vv.x + k4.y * vv.y + k4.z * vv.z + k4.w * vv.w;
            }
            s += __shfl_xor(s, 1);
            s += __shfl_xor(s, 2);
            float un = (1.0f / 128.0f) / (s + 1e-8f);
            u[k] = un;
            __syncthreads();
        }
        {   // v = nu / (Km^T @ u + 1e-8); t = m*2+q, q covers 64 k's
            const int m = t >> 1, q = t & 1;
            float s = 0.f;
            for (int k = 0; k < 64; k += 4) {
                float4 u4 = *(const float4*)&u[q * 64 + k];
                s += Kl[q * 64 + k + 0][m] * u4.x;
                s += Kl[q * 64 + k + 1][m] * u4.y;
                s += Kl[q * 64 + k + 2][m] * u4.z;
                s += Kl[q * 64 + k + 3][m] * u4.w;
            }
            s += __shfl_xor(s, 1);
            float vn = (1.0f / 256.0f) / (s + 1e-8f);
            v[m] = vn;
            __syncthreads();
        }
    }
    if (t < 128) UV[b * 384 + t] = u[t];
    if (t < 256) UV[b * 384 + 128 + t] = v[t];
}

// ---------------- K8b: T = u*Km*v, loss = sum(T*C)/B (full-chip parallel) ----------------
// grid 256 (16 batches x 16 k-chunks of 8 rows), block 256 (thread = m)
__global__ void k_tout(const float* __restrict__ C, const float* __restrict__ Km,
                       const float* __restrict__ UV, float* __restrict__ T,
                       float* __restrict__ loss) {
    __shared__ float red[4];
    const int b = blockIdx.x >> 4, kc = blockIdx.x & 15;
    const int t = threadIdx.x;
    const float* Kb = Km + (long)b * 32768;
    const float* Cb = C + (long)b * 32768;
    const float vv = UV[b * 384 + 128 + t];
    float part = 0.f;
#pragma unroll
    for (int i = 0; i < 8; i++) {
        const int k = kc * 8 + i;
        const float uu = UV[b * 384 + k];
        const long idx = (long)k * 256 + t;
        float tv = uu * Kb[idx] * vv;
        T[(long)b * 32768 + idx] = tv;
        part += tv * Cb[idx];
    }
    for (int o = 32; o > 0; o >>= 1) part += __shfl_xor(part, o);
    if ((t & 63) == 0) red[t >> 6] = part;
    __syncthreads();
    if (t == 0) atomicAdd(loss, (red[0] + red[1] + red[2] + red[3]) * (1.0f / 16.0f));
}

extern "C" void kernel_launch(void* const* d_in, const int* in_sizes, int n_in,
                              void* d_out, int out_size, void* d_ws, size_t ws_size,
                              hipStream_t stream) {
    const int*   ids  = (const int*)d_in[0];
    const float* vf   = (const float*)d_in[2];
    const float* emb  = (const float*)d_in[3];
    const float* WiF  = (const float*)d_in[4];
    const float* WhF  = (const float*)d_in[5];
    const float* biF  = (const float*)d_in[6];
    const float* bhF  = (const float*)d_in[7];
    const float* WiB  = (const float*)d_in[8];
    const float* WhB  = (const float*)d_in[9];
    const float* biB  = (const float*)d_in[10];
    const float* bhB  = (const float*)d_in[11];
    const float* tpW  = (const float*)d_in[12];
    const float* tpb  = (const float*)d_in[13];
    const float* vpW  = (const float*)d_in[14];
    const float* vpb  = (const float*)d_in[15];
    const float* tsW1 = (const float*)d_in[16];
    const float* tsb1 = (const float*)d_in[17];
    const float* tsw2 = (const float*)d_in[18];
    const float* tsb2 = (const float*)d_in[19];
    const float* vsW1 = (const float*)d_in[20];
    const float* vsb1 = (const float*)d_in[21];
    const float* vsw2 = (const float*)d_in[22];
    const float* vsb2 = (const float*)d_in[23];
    const float* vtW1 = (const float*)d_in[24];
    const float* vtb1 = (const float*)d_in[25];
    const float* vtw2 = (const float*)d_in[26];
    const float* vtb2 = (const float*)d_in[27];
    float* out = (float*)d_out;

    // workspace layout (bytes): total 60,817,408
    //   XGT bf16 [32][2048][384]  : 0           .. 50,331,648   (dead after 2nd k_scan3)
    //     Xb bf16 [4096][1024]    : 0           ..  8,388,608   (video overlay)
    //     Wb bf16 [768][1024]     : 8,388,608   ..  9,961,472
    //     G  f32  [4096][768]     : 9,961,472   .. 22,544,384   (dead after k_vepi)
    //       UV f32 [16][384]      : 9,961,472   ..  9,986,048   (sink overlay of G)
    //   embb bf16 + WibF + WibB   : 50,331,648  .. 58,341,888   (dead before E/V/C)
    //   E   f32  [2048][256]      : 50,331,648
    //   V   f32  [4096][256]      : 52,428,800
    //   C   f32  [16][128][256]   : 56,623,104
    //   Km  f32  [16][128][256]   : 58,720,256
    char* ws = (char*)d_ws;
    u16*   XGT = (u16*)ws;
    u16*   Xb = (u16*)ws;
    u16*   Wb = (u16*)(ws + 8388608);
    float* G  = (float*)(ws + 9961472);
    float* UVb = (float*)(ws + 9961472);
    u16*   embb = (u16*)(ws + 50331648);
    u16*   WibF = embb + 3906816;
    u16*   WibB = embb + 3955968;
    float* E  = (float*)(ws + 50331648);
    float* V  = (float*)(ws + 52428800);
    float* C  = (float*)(ws + 56623104);
    float* Km = (float*)(ws + 58720256);

    float* tf   = out + 2048;
    float* vseg = out + 526336;
    float* tsp  = out + 530432;
    float* vsp  = out + 532480;
    float* loss = out + 536576;
    float* T    = out + 536577;

    k_zero<<<8, 256, 0, stream>>>(out);

    // text path
    k_cvte<<<3912, 256, 0, stream>>>(emb, WiF, WiB, embb);
    k_xg2<<<dim3(512, 3), 256, 0, stream>>>(ids, embb, WibF, biF, XGT);
    k_scan3<<<256, 512, 0, stream>>>(XGT, WhF, bhF, tf, 0);
    k_xg2<<<dim3(512, 3), 256, 0, stream>>>(ids, embb, WibB, biB, XGT);
    k_scan3<<<256, 512, 0, stream>>>(XGT, WhB, bhB, tf, 1);

    // video path (overlays XGT region after scans)
    k_cvt<<<4864, 256, 0, stream>>>(vf, vsW1, vtW1, vpW, Xb, Wb);
    k_gemmv<<<dim3(32, 6), 256, 0, stream>>>(Xb, Wb, G);
    k_vepi<<<1024, 256, 0, stream>>>(G, vsb1, vsw2, vsb2, vtb1, vtw2, vtb2, vpb, V, vsp, vseg);

    k_tsum<<<2048, 128, 0, stream>>>(tf, tsW1, tsb1, tsw2, tsb2, tsp);
    k_eproj<<<256, 256, 0, stream>>>(tf, tsp, tpW, tpb, E);
    k_norm<<<1536, 256, 0, stream>>>(E, V);
    k_cost<<<dim3(16, 8), 256, 0, stream>>>(E, V, C, Km);
    k_sink2<<<16, 512, 0, stream>>>(Km, UVb);
    k_tout<<<256, 256, 0, stream>>>(C, Km, UVb, T, loss);
}